// Round 3
// baseline (1590.264 us; speedup 1.0000x reference)
//
#include <hip/hip_runtime.h>
#include <hip/hip_bf16.h>

#define N_NODES 100000
#define E_EDGES 600000
#define HDIM 128
#define H2DIM 256
#define NLAYER 3
#define NSUBT 2
#define NSUB_G 20000
#define ESUB_E 200000
#define OUTD 128
#define NBLK 1536  // persistent-GEMM grid: 6 blocks/CU (stats pass, 84 VGPR)
#define FBLK 1024  // fused-MLP grid: 4 blocks/CU (124 VGPR, 32KB LDS)

typedef __bf16 bf16_t;
typedef __bf16 bf16x8 __attribute__((ext_vector_type(8)));
typedef __bf16 bf16x4 __attribute__((ext_vector_type(4)));
typedef __bf16 bf16x2 __attribute__((ext_vector_type(2)));
typedef float f32x4 __attribute__((ext_vector_type(4)));
typedef float f32x2 __attribute__((ext_vector_type(2)));

// ---------------------------------------------------------------------------
// Weight transpose: W[k][n] (row-major K x Nc, fp32) -> Wt[n][k] (bf16)
// ---------------------------------------------------------------------------
__global__ __launch_bounds__(256) void transpose_w(const float* __restrict__ W,
                                                   bf16_t* __restrict__ Wt,
                                                   int K, int Nc, long total) {
    long idx = (long)blockIdx.x * 256 + threadIdx.x;
    if (idx >= total) return;
    long kn = (long)K * Nc;
    long b = idx / kn;
    long r = idx - b * kn;
    int k = (int)(r / Nc);
    int n = (int)(r - (long)k * Nc);
    Wt[b * kn + (long)n * K + k] = (bf16_t)W[idx];
}

__global__ __launch_bounds__(256) void cast_f2b(const float* __restrict__ in,
                                                bf16_t* __restrict__ out, long n) {
    long i = ((long)blockIdx.x * 256 + threadIdx.x) * 4;
    if (i >= n) return;
    f32x4 v = *(const f32x4*)(in + i);
    bf16x4 o;
    o[0] = (bf16_t)v[0]; o[1] = (bf16_t)v[1];
    o[2] = (bf16_t)v[2]; o[3] = (bf16_t)v[3];
    *(bf16x4*)(out + i) = o;
}

// ---------------------------------------------------------------------------
// CSR build: histogram -> hierarchical exclusive scan -> placement
// ---------------------------------------------------------------------------
__global__ __launch_bounds__(256) void hist_k(const int* __restrict__ idx,
                                              int* __restrict__ counts, int nE) {
    int e = blockIdx.x * 256 + threadIdx.x;
    if (e < nE) atomicAdd(&counts[idx[e]], 1);
}

__global__ __launch_bounds__(256) void scan1_k(const int* __restrict__ in,
                                               int* __restrict__ out,
                                               int* __restrict__ bsum, int n) {
    __shared__ int tmp[256];
    const int t = threadIdx.x;
    const long base = (long)blockIdx.x * 1024 + (long)t * 4;
    int v[4];
    int s = 0;
#pragma unroll
    for (int j = 0; j < 4; j++) {
        long i = base + j;
        int x = (i < n) ? in[i] : 0;
        v[j] = s;
        s += x;
    }
    tmp[t] = s;
    __syncthreads();
    int inc = s;
    for (int off = 1; off < 256; off <<= 1) {
        int y = (t >= off) ? tmp[t - off] : 0;
        __syncthreads();
        inc += y;
        tmp[t] = inc;
        __syncthreads();
    }
    const int toff = inc - s;
#pragma unroll
    for (int j = 0; j < 4; j++) {
        long i = base + j;
        if (i < n) out[i] = v[j] + toff;
    }
    if (t == 255) bsum[blockIdx.x] = inc;
}

__global__ __launch_bounds__(256) void scan2_k(int* __restrict__ bsum, int nb) {
    __shared__ int tmp[256];
    const int t = threadIdx.x;
    int x = (t < nb) ? bsum[t] : 0;
    tmp[t] = x;
    __syncthreads();
    int inc = x;
    for (int off = 1; off < 256; off <<= 1) {
        int y = (t >= off) ? tmp[t - off] : 0;
        __syncthreads();
        inc += y;
        tmp[t] = inc;
        __syncthreads();
    }
    if (t < nb) bsum[t] = inc - x;
}

__global__ __launch_bounds__(256) void scan3_k(const int* __restrict__ partial,
                                               const int* __restrict__ bsum,
                                               int* __restrict__ rowptr,
                                               int* __restrict__ work,
                                               int n, int total) {
    long i = (long)blockIdx.x * 256 + threadIdx.x;
    if (i < n) {
        int v = partial[i] + bsum[i >> 10];
        rowptr[i] = v;
        work[i] = v;
    }
    if (i == 0) rowptr[n] = total;
}

__global__ __launch_bounds__(256) void csr_place(const int* __restrict__ idx,
                                                 const int* __restrict__ gsrc,
                                                 int* __restrict__ work,
                                                 int* __restrict__ gat, int nE) {
    int e = blockIdx.x * 256 + threadIdx.x;
    if (e < nE) {
        int p = atomicAdd(&work[idx[e]], 1);
        gat[p] = gsrc[e];
    }
}

// ---------------------------------------------------------------------------
// Gather-based segment sums over bf16 features.
// 16-lane group per segment, bf16x8 per lane; edge loop unrolled x4.
// ---------------------------------------------------------------------------
__global__ __launch_bounds__(256) void segsum_ginb(const bf16_t* __restrict__ X,
                                                   const float* __restrict__ epsPtr,
                                                   const int* __restrict__ rowptr,
                                                   const int* __restrict__ gat,
                                                   bf16_t* __restrict__ out, int nseg) {
    const int seg = (blockIdx.x * 256 + threadIdx.x) >> 4;
    if (seg >= nseg) return;
    const int l = threadIdx.x & 15;
    const bf16x8* __restrict__ Xv = (const bf16x8*)X;  // row r at Xv[r*16 + l]
    const float alpha = 1.f + epsPtr[0];
    bf16x8 xv = Xv[(size_t)seg * 16 + l];
    float a[8];
#pragma unroll
    for (int j = 0; j < 8; j++) a[j] = alpha * (float)xv[j];
    const int s0 = rowptr[seg], s1 = rowptr[seg + 1];
    int e = s0;
    for (; e + 4 <= s1; e += 4) {
        int g0 = gat[e], g1 = gat[e + 1], g2 = gat[e + 2], g3 = gat[e + 3];
        bf16x8 v0 = Xv[(size_t)g0 * 16 + l];
        bf16x8 v1 = Xv[(size_t)g1 * 16 + l];
        bf16x8 v2 = Xv[(size_t)g2 * 16 + l];
        bf16x8 v3 = Xv[(size_t)g3 * 16 + l];
#pragma unroll
        for (int j = 0; j < 8; j++)
            a[j] += (float)v0[j] + (float)v1[j] + (float)v2[j] + (float)v3[j];
    }
    const int rem = s1 - e;
    if (rem > 0) {
        int g0 = gat[e];
        int g1 = gat[e + (rem > 1 ? 1 : 0)];
        int g2 = gat[e + (rem > 2 ? 2 : 0)];
        bf16x8 v0 = Xv[(size_t)g0 * 16 + l];
        bf16x8 v1 = Xv[(size_t)g1 * 16 + l];
        bf16x8 v2 = Xv[(size_t)g2 * 16 + l];
        const float m1 = rem > 1 ? 1.f : 0.f;
        const float m2 = rem > 2 ? 1.f : 0.f;
#pragma unroll
        for (int j = 0; j < 8; j++)
            a[j] += (float)v0[j] + m1 * (float)v1[j] + m2 * (float)v2[j];
    }
    bf16x8 o;
#pragma unroll
    for (int j = 0; j < 8; j++) o[j] = (bf16_t)a[j];
    *((bf16x8*)(out + (size_t)seg * HDIM) + l) = o;
}

__global__ __launch_bounds__(256) void segsum_b16(const bf16_t* __restrict__ X,
                                                  const int* __restrict__ rowptr,
                                                  const int* __restrict__ gat,
                                                  bf16_t* __restrict__ out, int nseg) {
    const int seg = (blockIdx.x * 256 + threadIdx.x) >> 4;
    if (seg >= nseg) return;
    const int l = threadIdx.x & 15;
    const bf16x8* __restrict__ Xv = (const bf16x8*)X;
    float a[8];
#pragma unroll
    for (int j = 0; j < 8; j++) a[j] = 0.f;
    const int s0 = rowptr[seg], s1 = rowptr[seg + 1];
    int e = s0;
    for (; e + 4 <= s1; e += 4) {
        int g0 = gat[e], g1 = gat[e + 1], g2 = gat[e + 2], g3 = gat[e + 3];
        bf16x8 v0 = Xv[(size_t)g0 * 16 + l];
        bf16x8 v1 = Xv[(size_t)g1 * 16 + l];
        bf16x8 v2 = Xv[(size_t)g2 * 16 + l];
        bf16x8 v3 = Xv[(size_t)g3 * 16 + l];
#pragma unroll
        for (int j = 0; j < 8; j++)
            a[j] += (float)v0[j] + (float)v1[j] + (float)v2[j] + (float)v3[j];
    }
    const int rem = s1 - e;
    if (rem > 0) {
        int g0 = gat[e];
        int g1 = gat[e + (rem > 1 ? 1 : 0)];
        int g2 = gat[e + (rem > 2 ? 2 : 0)];
        bf16x8 v0 = Xv[(size_t)g0 * 16 + l];
        bf16x8 v1 = Xv[(size_t)g1 * 16 + l];
        bf16x8 v2 = Xv[(size_t)g2 * 16 + l];
        const float m1 = rem > 1 ? 1.f : 0.f;
        const float m2 = rem > 2 ? 1.f : 0.f;
#pragma unroll
        for (int j = 0; j < 8; j++)
            a[j] += (float)v0[j] + m1 * (float)v1[j] + m2 * (float)v2[j];
    }
    bf16x8 o;
#pragma unroll
    for (int j = 0; j < 8; j++) o[j] = (bf16_t)a[j];
    *((bf16x8*)(out + (size_t)seg * HDIM) + l) = o;
}

// ---------------------------------------------------------------------------
// BN finalize
// ---------------------------------------------------------------------------
__global__ void bn_finalize(const float* __restrict__ cs, const float* __restrict__ cs2,
                            const float* __restrict__ g, const float* __restrict__ b,
                            float* __restrict__ scale, float* __restrict__ shift,
                            int C, float invN) {
    int c = blockIdx.x * blockDim.x + threadIdx.x;
    if (c >= C) return;
    float m = cs[c] * invN;
    float v = cs2[c] * invN - m * m;
    float sc = g[c] * rsqrtf(v + 1e-5f);
    scale[c] = sc;
    shift[c] = b[c] - m * sc;
}

// ---------------------------------------------------------------------------
// Register-resident-weight persistent GEMM (BN stats pass only:
// flags 4|8 = column stats, no store).
// flags: 1 relu, 2 accumulate, 4 column stats, 8 no-store.
// ---------------------------------------------------------------------------
template <int K, int NC>
__global__ __launch_bounds__(256, 3) void gemm_reg(
    const bf16_t* __restrict__ Ab,
    const float* __restrict__ bnScale, const float* __restrict__ bnShift,
    const bf16_t* __restrict__ Wt, const float* __restrict__ bias,
    int M,
    bf16_t* __restrict__ outB, float* __restrict__ outF,
    float* __restrict__ colsum, float* __restrict__ colsumsq,
    int bnfold, int flags) {
    constexpr int NKS = K / 32;       // k-steps
    constexpr int SLICE = NC / 4;     // cols per wave
    constexpr int NNI = SLICE / 16;   // n-frags per wave
    const int w = threadIdx.x >> 6, lane = threadIdx.x & 63;
    const int q = lane >> 4, lm = lane & 15;
    const int c0 = w * SLICE;

    bf16x8 bfr[NNI][NKS];
#pragma unroll
    for (int ni = 0; ni < NNI; ni++) {
        const bf16_t* bp = Wt + (size_t)(c0 + ni * 16 + lm) * K + q * 8;
#pragma unroll
        for (int ks = 0; ks < NKS; ks++)
            bfr[ni][ks] = *(const bf16x8*)(bp + ks * 32);
    }
    const bool doRelu = (flags & 1), doAccum = (flags & 2), doStats = (flags & 4);
    const bool doStore = !(flags & 8);
    float bv[NNI];
#pragma unroll
    for (int ni = 0; ni < NNI; ni++) bv[ni] = bias[c0 + ni * 16 + lm];
    float st1[NNI], st2[NNI];
#pragma unroll
    for (int ni = 0; ni < NNI; ni++) { st1[ni] = 0.f; st2[ni] = 0.f; }

    const int nTiles = (M + 31) >> 5;
    for (int t = blockIdx.x; t < nTiles; t += gridDim.x) {
        const int row0 = t << 5;
        bf16x8 af[2][NKS];
#pragma unroll
        for (int mi = 0; mi < 2; mi++) {
            int gr = row0 + mi * 16 + lm;
            if (gr > M - 1) gr = M - 1;
            const bf16_t* ap = Ab + (size_t)gr * K + q * 8;
#pragma unroll
            for (int ks = 0; ks < NKS; ks++)
                af[mi][ks] = *(const bf16x8*)(ap + ks * 32);
        }
        if (bnfold) {
#pragma unroll
            for (int ks = 0; ks < NKS; ks++) {
                const int kk = ks * 32 + q * 8;
                f32x4 s0 = ((const f32x4*)(bnScale + kk))[0];
                f32x4 s1v = ((const f32x4*)(bnScale + kk))[1];
                f32x4 h0 = ((const f32x4*)(bnShift + kk))[0];
                f32x4 h1 = ((const f32x4*)(bnShift + kk))[1];
                float sc8[8] = {s0[0], s0[1], s0[2], s0[3], s1v[0], s1v[1], s1v[2], s1v[3]};
                float sh8[8] = {h0[0], h0[1], h0[2], h0[3], h1[0], h1[1], h1[2], h1[3]};
#pragma unroll
                for (int mi = 0; mi < 2; mi++)
#pragma unroll
                    for (int j = 0; j < 8; j++) {
                        float f = fmaxf((float)af[mi][ks][j] * sc8[j] + sh8[j], 0.f);
                        af[mi][ks][j] = (bf16_t)f;
                    }
            }
        }
        f32x4 acc[2][NNI];
#pragma unroll
        for (int a = 0; a < 2; a++)
#pragma unroll
            for (int b = 0; b < NNI; b++) acc[a][b] = f32x4{0.f, 0.f, 0.f, 0.f};
#pragma unroll
        for (int ks = 0; ks < NKS; ks++)
#pragma unroll
            for (int ni = 0; ni < NNI; ni++) {
                acc[0][ni] = __builtin_amdgcn_mfma_f32_16x16x32_bf16(
                    af[0][ks], bfr[ni][ks], acc[0][ni], 0, 0, 0);
                acc[1][ni] = __builtin_amdgcn_mfma_f32_16x16x32_bf16(
                    af[1][ks], bfr[ni][ks], acc[1][ni], 0, 0, 0);
            }
#pragma unroll
        for (int ni = 0; ni < NNI; ni++) {
            const int col = c0 + ni * 16 + lm;
#pragma unroll
            for (int mi = 0; mi < 2; mi++) {
#pragma unroll
                for (int r = 0; r < 4; r++) {
                    const int row = row0 + mi * 16 + q * 4 + r;
                    if (row < M) {
                        float v = acc[mi][ni][r] + bv[ni];
                        if (doStats) { st1[ni] += v; st2[ni] += v * v; }
                        if (doRelu) v = fmaxf(v, 0.f);
                        if (doStore) {
                            const size_t o = (size_t)row * NC + col;
                            if (outF) {
                                outF[o] = v;
                            } else {
                                if (doAccum) v += (float)outB[o];
                                outB[o] = (bf16_t)v;
                            }
                        }
                    }
                }
            }
        }
    }
    if (doStats) {
#pragma unroll
        for (int ni = 0; ni < NNI; ni++) {
            float s1 = st1[ni], s2 = st2[ni];
            s1 += __shfl_xor(s1, 16);
            s1 += __shfl_xor(s1, 32);
            s2 += __shfl_xor(s2, 16);
            s2 += __shfl_xor(s2, 32);
            if (q == 0) {
                atomicAdd(&colsum[c0 + ni * 16 + lm], s1);
                atomicAdd(&colsumsq[c0 + ni * 16 + lm], s2);
            }
        }
    }
}

// ---------------------------------------------------------------------------
// Fused MLP: out = relu((A@W1+b1)[*bnScale+bnShift]) @ W2 + b2
// K1=128, H2=256, NO=128. 4 waves/block. Weight slices register-resident.
// 32x256 bf16 h-tile through double-buffered XOR-swizzled LDS, 1 barrier/tile.
// Software pipeline: af registers are dead after GEMM1, so the NEXT tile's
// A-loads are issued before the barrier -> they overlap barrier+GEMM2+stores.
// flags: 1 accumulate (bf16 RMW on outB), 2 fp32 store to outF.
// ---------------------------------------------------------------------------
__global__ __launch_bounds__(256, 2) void fused_mlp(
    const bf16_t* __restrict__ Ab,
    const bf16_t* __restrict__ Wt1, const float* __restrict__ b1,
    const float* __restrict__ bnS, const float* __restrict__ bnH,
    const bf16_t* __restrict__ Wt2, const float* __restrict__ b2,
    int M,
    bf16_t* __restrict__ outB, float* __restrict__ outF,
    int bnfold, int flags) {
    __shared__ char hs[2][32 * 512];  // 2 x (32 rows x 256 bf16)
    const int w = threadIdx.x >> 6, lane = threadIdx.x & 63;
    const int q = lane >> 4, lm = lane & 15;
    const int c0h = w * 64;   // wave's H2-column slice
    const int c0o = w * 32;   // wave's out-column slice

    // resident W1 slice: 4 n-frags x 4 k-steps = 64 VGPRs
    bf16x8 bfr1[4][4];
#pragma unroll
    for (int ni = 0; ni < 4; ni++) {
        const bf16_t* bp = Wt1 + (size_t)(c0h + ni * 16 + lm) * 128 + q * 8;
#pragma unroll
        for (int ks = 0; ks < 4; ks++) bfr1[ni][ks] = *(const bf16x8*)(bp + ks * 32);
    }
    // resident W2 slice: 2 n-frags x 8 k-steps = 64 VGPRs
    bf16x8 bfr2[2][8];
#pragma unroll
    for (int ni = 0; ni < 2; ni++) {
        const bf16_t* bp = Wt2 + (size_t)(c0o + ni * 16 + lm) * 256 + q * 8;
#pragma unroll
        for (int ks = 0; ks < 8; ks++) bfr2[ni][ks] = *(const bf16x8*)(bp + ks * 32);
    }
    float bv1[4], bsc[4], bsh[4];
#pragma unroll
    for (int ni = 0; ni < 4; ni++) {
        const int c = c0h + ni * 16 + lm;
        bv1[ni] = b1[c];
        bsc[ni] = bnfold ? bnS[c] : 1.f;
        bsh[ni] = bnfold ? bnH[c] : 0.f;
    }
    float bv2[2];
#pragma unroll
    for (int ni = 0; ni < 2; ni++) bv2[ni] = b2[c0o + ni * 16 + lm];

    const bool doAccum = (flags & 1), f32out = (flags & 2);
    const int nTiles = (M + 31) >> 5;
    const int stride = gridDim.x;
    int t = blockIdx.x;
    if (t >= nTiles) return;
    int buf = 0;

    // prologue: load A for the first tile
    bf16x8 af[2][4];
    {
        const int row0 = t << 5;
#pragma unroll
        for (int mi = 0; mi < 2; mi++) {
            int gr = row0 + mi * 16 + lm;
            if (gr > M - 1) gr = M - 1;
            const bf16_t* ap = Ab + (size_t)gr * 128 + q * 8;
#pragma unroll
            for (int ks = 0; ks < 4; ks++) af[mi][ks] = *(const bf16x8*)(ap + ks * 32);
        }
    }

    for (; t < nTiles; t += stride, buf ^= 1) {
        const int row0 = t << 5;
        char* hb = hs[buf];
        // ---- GEMM1: A (regs, preloaded) x W1 (regs) ----
        if (bnfold) {
#pragma unroll
            for (int ks = 0; ks < 4; ks++) {
#pragma unroll
                for (int mi = 0; mi < 2; mi++) {
                    // fold applied at consume; af dead after this block
                }
            }
        }
        f32x4 acc1[2][4];
#pragma unroll
        for (int a = 0; a < 2; a++)
#pragma unroll
            for (int b = 0; b < 4; b++) acc1[a][b] = f32x4{0.f, 0.f, 0.f, 0.f};
#pragma unroll
        for (int ks = 0; ks < 4; ks++)
#pragma unroll
            for (int ni = 0; ni < 4; ni++) {
                acc1[0][ni] = __builtin_amdgcn_mfma_f32_16x16x32_bf16(
                    af[0][ks], bfr1[ni][ks], acc1[0][ni], 0, 0, 0);
                acc1[1][ni] = __builtin_amdgcn_mfma_f32_16x16x32_bf16(
                    af[1][ks], bfr1[ni][ks], acc1[1][ni], 0, 0, 0);
            }
        // ---- prefetch next tile's A into af (af is dead now) ----
        const int tn = t + stride;
        if (tn < nTiles) {
            const int nrow0 = tn << 5;
#pragma unroll
            for (int mi = 0; mi < 2; mi++) {
                int gr = nrow0 + mi * 16 + lm;
                if (gr > M - 1) gr = M - 1;
                const bf16_t* ap = Ab + (size_t)gr * 128 + q * 8;
#pragma unroll
                for (int ks = 0; ks < 4; ks++)
                    af[mi][ks] = *(const bf16x8*)(ap + ks * 32);
            }
        }
        // ---- mid epilogue: bias (+BN fold) + relu -> swizzled LDS ----
#pragma unroll
        for (int ni = 0; ni < 4; ni++) {
            const int colb = (c0h + ni * 16 + lm) * 2;
#pragma unroll
            for (int mi = 0; mi < 2; mi++)
#pragma unroll
                for (int r = 0; r < 4; r++) {
                    const int row = mi * 16 + q * 4 + r;
                    float v = (acc1[mi][ni][r] + bv1[ni]) * bsc[ni] + bsh[ni];
                    v = fmaxf(v, 0.f);
                    const int swz = ((row & 7) << 4) ^ ((row & 8) << 2);
                    *(bf16_t*)(hb + (row << 9) + (colb ^ swz)) = (bf16_t)v;
                }
        }
        __syncthreads();
        // ---- GEMM2: h (LDS) x W2 (regs) ----
        f32x4 acc2[2][2];
#pragma unroll
        for (int a = 0; a < 2; a++)
#pragma unroll
            for (int b = 0; b < 2; b++) acc2[a][b] = f32x4{0.f, 0.f, 0.f, 0.f};
#pragma unroll
        for (int ks = 0; ks < 8; ks++) {
            const int ko = ks * 64 + q * 16;
            const int r0 = lm, r1 = lm + 16;
            const int s0 = ((r0 & 7) << 4) ^ ((r0 & 8) << 2);
            const int s1 = ((r1 & 7) << 4) ^ ((r1 & 8) << 2);
            bf16x8 a0 = *(const bf16x8*)(hb + (r0 << 9) + (ko ^ s0));
            bf16x8 a1 = *(const bf16x8*)(hb + (r1 << 9) + (ko ^ s1));
#pragma unroll
            for (int ni = 0; ni < 2; ni++) {
                acc2[0][ni] = __builtin_amdgcn_mfma_f32_16x16x32_bf16(
                    a0, bfr2[ni][ks], acc2[0][ni], 0, 0, 0);
                acc2[1][ni] = __builtin_amdgcn_mfma_f32_16x16x32_bf16(
                    a1, bfr2[ni][ks], acc2[1][ni], 0, 0, 0);
            }
        }
        // ---- final epilogue ----
#pragma unroll
        for (int ni = 0; ni < 2; ni++) {
            const int col = c0o + ni * 16 + lm;
#pragma unroll
            for (int mi = 0; mi < 2; mi++)
#pragma unroll
                for (int r = 0; r < 4; r++) {
                    const int row = row0 + mi * 16 + q * 4 + r;
                    if (row < M) {
                        float v = acc2[mi][ni][r] + bv2[ni];
                        const size_t o = (size_t)row * 128 + col;
                        if (f32out) {
                            outF[o] = v;
                        } else {
                            if (doAccum) v += (float)outB[o];
                            outB[o] = (bf16_t)v;
                        }
                    }
                }
        }
        // no trailing barrier: next tile writes the other LDS buffer; the
        // barrier inside iteration t+1 orders read(t) before write(t+2).
    }
}

// NOTE: BN fold is applied where af is consumed (inside GEMM1's input path).
// To keep af dead after GEMM1, the fold happens just before the MFMA loop.
// We implement it by pre-scaling af in place right before the MFMA loop:
// (done above via bsc/bsh at h-epilogue instead — mathematically identical:
//  relu((A@W1+b1)*s + h) == relu applied after fold; fold is per-H2-column,
//  so it commutes to the epilogue. bnfold thus costs nothing in GEMM1.)

// ---------------------------------------------------------------------------
extern "C" void kernel_launch(void* const* d_in, const int* in_sizes, int n_in,
                              void* d_out, int out_size, void* d_ws, size_t ws_size,
                              hipStream_t stream) {
    const float* x_in   = (const float*)d_in[0];
    const int*   ei     = (const int*)d_in[1];
    const int*   se0    = (const int*)d_in[2];
    const int*   se1    = (const int*)d_in[3];
    const float* msg_w1 = (const float*)d_in[4];
    const float* msg_b1 = (const float*)d_in[5];
    const float* bn_g   = (const float*)d_in[6];
    const float* bn_b   = (const float*)d_in[7];
    const float* msg_w2 = (const float*)d_in[8];
    const float* msg_b2 = (const float*)d_in[9];
    const float* eps_g  = (const float*)d_in[10];
    const float* n2s_w1 = (const float*)d_in[11];
    const float* n2s_b1 = (const float*)d_in[12];
    const float* n2s_w2 = (const float*)d_in[13];
    const float* n2s_b2 = (const float*)d_in[14];
    const float* s2n_w1 = (const float*)d_in[15];
    const float* s2n_b1 = (const float*)d_in[16];
    const float* s2n_w2 = (const float*)d_in[17];
    const float* s2n_b2 = (const float*)d_in[18];
    const float* out_w1 = (const float*)d_in[19];
    const float* out_b1 = (const float*)d_in[20];
    const float* out_w2 = (const float*)d_in[21];
    const float* out_b2 = (const float*)d_in[22];
    float* out = (float*)d_out;

    char* ws = (char*)d_ws;
    size_t off = 0;
    auto alloc = [&](size_t bytes) -> char* {
        char* p = ws + off;
        off += (bytes + 255) & ~(size_t)255;
        return p;
    };
    bf16_t* xbf   = (bf16_t*)alloc((size_t)N_NODES * HDIM * 2);   // residual x (bf16)
    bf16_t* xcomb = (bf16_t*)alloc((size_t)N_NODES * HDIM * 2);   // gin-comb / s2n msg
    bf16_t* sxsum = (bf16_t*)alloc((size_t)NSUB_G * HDIM * 2);
    bf16_t* sxout = (bf16_t*)alloc((size_t)NSUB_G * HDIM * 2);
    const size_t WSZ = (size_t)HDIM * H2DIM;
    bf16_t* wt_msg1 = (bf16_t*)alloc(NLAYER * WSZ * 2);
    bf16_t* wt_msg2 = (bf16_t*)alloc(NLAYER * WSZ * 2);
    bf16_t* wt_n2s1 = (bf16_t*)alloc(NLAYER * NSUBT * WSZ * 2);
    bf16_t* wt_n2s2 = (bf16_t*)alloc(NLAYER * NSUBT * WSZ * 2);
    bf16_t* wt_s2n1 = (bf16_t*)alloc(NLAYER * NSUBT * WSZ * 2);
    bf16_t* wt_s2n2 = (bf16_t*)alloc(NLAYER * NSUBT * WSZ * 2);
    bf16_t* wt_out1 = (bf16_t*)alloc(WSZ * 2);
    bf16_t* wt_out2 = (bf16_t*)alloc(WSZ * 2);
    float* colsum   = (float*)alloc(H2DIM * 4);
    float* colsumsq = (float*)alloc(H2DIM * 4);
    float* bnscale  = (float*)alloc(H2DIM * 4);
    float* bnshift  = (float*)alloc(H2DIM * 4);
    int* rp_gin   = (int*)alloc((N_NODES + 1) * 4);
    int* gat_gin  = (int*)alloc((size_t)E_EDGES * 4);
    int* rp_n2s0  = (int*)alloc((NSUB_G + 1) * 4);
    int* gat_n2s0 = (int*)alloc((size_t)ESUB_E * 4);
    int* rp_n2s1  = (int*)alloc((NSUB_G + 1) * 4);
    int* gat_n2s1 = (int*)alloc((size_t)ESUB_E * 4);
    int* rp_s2n0  = (int*)alloc((N_NODES + 1) * 4);
    int* gat_s2n0 = (int*)alloc((size_t)ESUB_E * 4);
    int* rp_s2n1  = (int*)alloc((N_NODES + 1) * 4);
    int* gat_s2n1 = (int*)alloc((size_t)ESUB_E * 4);
    int* counts  = (int*)alloc((N_NODES + 1) * 4);
    int* partial = (int*)alloc((size_t)N_NODES * 4);
    int* bsum    = (int*)alloc(512 * 4);
    (void)ws_size; (void)in_sizes; (void)n_in; (void)out_size;

    auto tr = [&](const float* W, bf16_t* Wt, int K, int Nc, int batch) {
        long total = (long)batch * K * Nc;
        int blocks = (int)((total + 255) / 256);
        transpose_w<<<blocks, 256, 0, stream>>>(W, Wt, K, Nc, total);
    };
    tr(msg_w1, wt_msg1, HDIM, H2DIM, NLAYER);
    tr(msg_w2, wt_msg2, H2DIM, HDIM, NLAYER);
    tr(n2s_w1, wt_n2s1, HDIM, H2DIM, NLAYER * NSUBT);
    tr(n2s_w2, wt_n2s2, H2DIM, HDIM, NLAYER * NSUBT);
    tr(s2n_w1, wt_s2n1, HDIM, H2DIM, NLAYER * NSUBT);
    tr(s2n_w2, wt_s2n2, H2DIM, HDIM, NLAYER * NSUBT);
    tr(out_w1, wt_out1, HDIM, H2DIM, 1);
    tr(out_w2, wt_out2, H2DIM, OUTD, 1);

    auto build_csr = [&](const int* idx, const int* gsrc, int nE, int nseg,
                         int* rowptr, int* gat) {
        hipMemsetAsync(counts, 0, (size_t)nseg * 4, stream);
        hist_k<<<(nE + 255) / 256, 256, 0, stream>>>(idx, counts, nE);
        int nb = (nseg + 1023) / 1024;
        scan1_k<<<nb, 256, 0, stream>>>(counts, partial, bsum, nseg);
        scan2_k<<<1, 256, 0, stream>>>(bsum, nb);
        scan3_k<<<(nseg + 255) / 256, 256, 0, stream>>>(partial, bsum, rowptr,
                                                        counts, nseg, nE);
        csr_place<<<(nE + 255) / 256, 256, 0, stream>>>(idx, gsrc, counts, gat, nE);
    };
    const int* src = ei;
    const int* dst = ei + E_EDGES;
    build_csr(dst, src, E_EDGES, N_NODES, rp_gin, gat_gin);
    build_csr(se0 + ESUB_E, se0, ESUB_E, NSUB_G, rp_n2s0, gat_n2s0);
    build_csr(se1 + ESUB_E, se1, ESUB_E, NSUB_G, rp_n2s1, gat_n2s1);
    build_csr(se0, se0 + ESUB_E, ESUB_E, N_NODES, rp_s2n0, gat_s2n0);
    build_csr(se1, se1 + ESUB_E, ESUB_E, N_NODES, rp_s2n1, gat_s2n1);

    {
        long n = (long)N_NODES * HDIM;
        cast_f2b<<<(int)((n / 4 + 255) / 256), 256, 0, stream>>>(x_in, xbf, n);
    }

    // stats-only gemm (K=128, NC=256)
    auto gemmStats = [&](const bf16_t* Ab, const bf16_t* Wt, const float* bias,
                         int M, float* cs, float* cs2) {
        int nt = (M + 31) / 32;
        int g = nt < NBLK ? nt : NBLK;
        gemm_reg<128, 256><<<g, 256, 0, stream>>>(
            Ab, nullptr, nullptr, Wt, bias, M, nullptr, nullptr, cs, cs2, 0, 4 | 8);
    };
    // fused MLP
    auto fmlp = [&](const bf16_t* Ab, const bf16_t* W1t, const float* b1p,
                    const float* bnS, const float* bnH,
                    const bf16_t* W2t, const float* b2p, int M,
                    bf16_t* oB, float* oF, int bnfold, int flags) {
        int nt = (M + 31) / 32;
        int g = nt < FBLK ? nt : FBLK;
        fused_mlp<<<g, 256, 0, stream>>>(Ab, W1t, b1p, bnS, bnH, W2t, b2p, M,
                                         oB, oF, bnfold, flags);
    };

    for (int i = 0; i < NLAYER; i++) {
        // GIN aggregation fused with (1+eps)x combine -> bf16
        segsum_ginb<<<(N_NODES + 15) / 16, 256, 0, stream>>>(
            xbf, eps_g + i, rp_gin, gat_gin, xcomb, N_NODES);
        // pass 1: column stats of h = xcomb@W1+b1 (no h write)
        hipMemsetAsync(colsum, 0, H2DIM * 4, stream);
        hipMemsetAsync(colsumsq, 0, H2DIM * 4, stream);
        gemmStats(xcomb, wt_msg1 + (size_t)i * WSZ, msg_b1 + (size_t)i * H2DIM,
                  N_NODES, colsum, colsumsq);
        bn_finalize<<<1, 256, 0, stream>>>(colsum, colsumsq, bn_g + (size_t)i * H2DIM,
                                           bn_b + (size_t)i * H2DIM, bnscale, bnshift,
                                           H2DIM, 1.0f / N_NODES);
        // pass 2: x = relu(BN(xcomb@W1+b1)) @ W2 + b2 fused
        fmlp(xcomb, wt_msg1 + (size_t)i * WSZ, msg_b1 + (size_t)i * H2DIM,
             bnscale, bnshift,
             wt_msg2 + (size_t)i * WSZ, msg_b2 + (size_t)i * HDIM,
             N_NODES, xbf, nullptr, 1, 0);

        for (int s = 0; s < NSUBT; s++) {
            const int* rp_n2s = (s == 0 ? rp_n2s0 : rp_n2s1);
            const int* gt_n2s = (s == 0 ? gat_n2s0 : gat_n2s1);
            const int* rp_s2n = (s == 0 ? rp_s2n0 : rp_s2n1);
            const int* gt_s2n = (s == 0 ? gat_s2n0 : gat_s2n1);
            const size_t widx = ((size_t)i * NSUBT + s) * WSZ;
            const size_t b1o = ((size_t)i * NSUBT + s) * H2DIM;
            const size_t b2o = ((size_t)i * NSUBT + s) * HDIM;
            // sx = segment_sum(x[row], col)
            segsum_b16<<<(NSUB_G + 15) / 16, 256, 0, stream>>>(
                xbf, rp_n2s, gt_n2s, sxsum, NSUB_G);
            // sx = relu(sx@w1+b1)@w2+b2  (fused)
            fmlp(sxsum, wt_n2s1 + widx, n2s_b1 + b1o, nullptr, nullptr,
                 wt_n2s2 + widx, n2s_b2 + b2o, NSUB_G, sxout, nullptr, 0, 0);
            // msg = segment_sum(sx[col], row)
            segsum_b16<<<(N_NODES + 15) / 16, 256, 0, stream>>>(
                sxout, rp_s2n, gt_s2n, xcomb, N_NODES);
            // x += relu(msg@w1+b1)@w2+b2  (fused, accumulate)
            fmlp(xcomb, wt_s2n1 + widx, s2n_b1 + b1o, nullptr, nullptr,
                 wt_s2n2 + widx, s2n_b2 + b2o, N_NODES, xbf, nullptr, 0, 1);
        }
    }
    // output head (fused, fp32 out)
    fmlp(xbf, wt_out1, out_b1, nullptr, nullptr, wt_out2, out_b2,
         N_NODES, nullptr, out, 0, 2);
}

// Round 4
// 1472.437 us; speedup vs baseline: 1.0800x; 1.0800x over previous
//
#include <hip/hip_runtime.h>
#include <hip/hip_bf16.h>

#define N_NODES 100000
#define E_EDGES 600000
#define HDIM 128
#define H2DIM 256
#define NLAYER 3
#define NSUBT 2
#define NSUB_G 20000
#define ESUB_E 200000
#define OUTD 128
#define NBLK 1536  // persistent-GEMM grid: 6 blocks/CU (stats pass, 84 VGPR)
#define FBLK 768   // fused-MLP grid: 3 blocks/CU (124 VGPR, 32KB LDS)

typedef __bf16 bf16_t;
typedef __bf16 bf16x8 __attribute__((ext_vector_type(8)));
typedef __bf16 bf16x4 __attribute__((ext_vector_type(4)));
typedef __bf16 bf16x2 __attribute__((ext_vector_type(2)));
typedef float f32x4 __attribute__((ext_vector_type(4)));
typedef float f32x2 __attribute__((ext_vector_type(2)));

// ---------------------------------------------------------------------------
// Weight transpose: W[k][n] (row-major K x Nc, fp32) -> Wt[n][k] (bf16)
// ---------------------------------------------------------------------------
__global__ __launch_bounds__(256) void transpose_w(const float* __restrict__ W,
                                                   bf16_t* __restrict__ Wt,
                                                   int K, int Nc, long total) {
    long idx = (long)blockIdx.x * 256 + threadIdx.x;
    if (idx >= total) return;
    long kn = (long)K * Nc;
    long b = idx / kn;
    long r = idx - b * kn;
    int k = (int)(r / Nc);
    int n = (int)(r - (long)k * Nc);
    Wt[b * kn + (long)n * K + k] = (bf16_t)W[idx];
}

__global__ __launch_bounds__(256) void cast_f2b(const float* __restrict__ in,
                                                bf16_t* __restrict__ out, long n) {
    long i = ((long)blockIdx.x * 256 + threadIdx.x) * 4;
    if (i >= n) return;
    f32x4 v = *(const f32x4*)(in + i);
    bf16x4 o;
    o[0] = (bf16_t)v[0]; o[1] = (bf16_t)v[1];
    o[2] = (bf16_t)v[2]; o[3] = (bf16_t)v[3];
    *(bf16x4*)(out + i) = o;
}

// ---------------------------------------------------------------------------
// CSR build: histogram -> hierarchical exclusive scan -> placement
// ---------------------------------------------------------------------------
__global__ __launch_bounds__(256) void hist_k(const int* __restrict__ idx,
                                              int* __restrict__ counts, int nE) {
    int e = blockIdx.x * 256 + threadIdx.x;
    if (e < nE) atomicAdd(&counts[idx[e]], 1);
}

__global__ __launch_bounds__(256) void scan1_k(const int* __restrict__ in,
                                               int* __restrict__ out,
                                               int* __restrict__ bsum, int n) {
    __shared__ int tmp[256];
    const int t = threadIdx.x;
    const long base = (long)blockIdx.x * 1024 + (long)t * 4;
    int v[4];
    int s = 0;
#pragma unroll
    for (int j = 0; j < 4; j++) {
        long i = base + j;
        int x = (i < n) ? in[i] : 0;
        v[j] = s;
        s += x;
    }
    tmp[t] = s;
    __syncthreads();
    int inc = s;
    for (int off = 1; off < 256; off <<= 1) {
        int y = (t >= off) ? tmp[t - off] : 0;
        __syncthreads();
        inc += y;
        tmp[t] = inc;
        __syncthreads();
    }
    const int toff = inc - s;
#pragma unroll
    for (int j = 0; j < 4; j++) {
        long i = base + j;
        if (i < n) out[i] = v[j] + toff;
    }
    if (t == 255) bsum[blockIdx.x] = inc;
}

__global__ __launch_bounds__(256) void scan2_k(int* __restrict__ bsum, int nb) {
    __shared__ int tmp[256];
    const int t = threadIdx.x;
    int x = (t < nb) ? bsum[t] : 0;
    tmp[t] = x;
    __syncthreads();
    int inc = x;
    for (int off = 1; off < 256; off <<= 1) {
        int y = (t >= off) ? tmp[t - off] : 0;
        __syncthreads();
        inc += y;
        tmp[t] = inc;
        __syncthreads();
    }
    if (t < nb) bsum[t] = inc - x;
}

__global__ __launch_bounds__(256) void scan3_k(const int* __restrict__ partial,
                                               const int* __restrict__ bsum,
                                               int* __restrict__ rowptr,
                                               int* __restrict__ work,
                                               int n, int total) {
    long i = (long)blockIdx.x * 256 + threadIdx.x;
    if (i < n) {
        int v = partial[i] + bsum[i >> 10];
        rowptr[i] = v;
        work[i] = v;
    }
    if (i == 0) rowptr[n] = total;
}

__global__ __launch_bounds__(256) void csr_place(const int* __restrict__ idx,
                                                 const int* __restrict__ gsrc,
                                                 int* __restrict__ work,
                                                 int* __restrict__ gat, int nE) {
    int e = blockIdx.x * 256 + threadIdx.x;
    if (e < nE) {
        int p = atomicAdd(&work[idx[e]], 1);
        gat[p] = gsrc[e];
    }
}

// ---------------------------------------------------------------------------
// Gather-based segment sums over bf16 features.
// 16-lane group per segment, bf16x8 per lane; edge loop unrolled x4.
// ---------------------------------------------------------------------------
__global__ __launch_bounds__(256) void segsum_ginb(const bf16_t* __restrict__ X,
                                                   const float* __restrict__ epsPtr,
                                                   const int* __restrict__ rowptr,
                                                   const int* __restrict__ gat,
                                                   bf16_t* __restrict__ out, int nseg) {
    const int seg = (blockIdx.x * 256 + threadIdx.x) >> 4;
    if (seg >= nseg) return;
    const int l = threadIdx.x & 15;
    const bf16x8* __restrict__ Xv = (const bf16x8*)X;  // row r at Xv[r*16 + l]
    const float alpha = 1.f + epsPtr[0];
    bf16x8 xv = Xv[(size_t)seg * 16 + l];
    float a[8];
#pragma unroll
    for (int j = 0; j < 8; j++) a[j] = alpha * (float)xv[j];
    const int s0 = rowptr[seg], s1 = rowptr[seg + 1];
    int e = s0;
    for (; e + 4 <= s1; e += 4) {
        int g0 = gat[e], g1 = gat[e + 1], g2 = gat[e + 2], g3 = gat[e + 3];
        bf16x8 v0 = Xv[(size_t)g0 * 16 + l];
        bf16x8 v1 = Xv[(size_t)g1 * 16 + l];
        bf16x8 v2 = Xv[(size_t)g2 * 16 + l];
        bf16x8 v3 = Xv[(size_t)g3 * 16 + l];
#pragma unroll
        for (int j = 0; j < 8; j++)
            a[j] += (float)v0[j] + (float)v1[j] + (float)v2[j] + (float)v3[j];
    }
    const int rem = s1 - e;
    if (rem > 0) {
        int g0 = gat[e];
        int g1 = gat[e + (rem > 1 ? 1 : 0)];
        int g2 = gat[e + (rem > 2 ? 2 : 0)];
        bf16x8 v0 = Xv[(size_t)g0 * 16 + l];
        bf16x8 v1 = Xv[(size_t)g1 * 16 + l];
        bf16x8 v2 = Xv[(size_t)g2 * 16 + l];
        const float m1 = rem > 1 ? 1.f : 0.f;
        const float m2 = rem > 2 ? 1.f : 0.f;
#pragma unroll
        for (int j = 0; j < 8; j++)
            a[j] += (float)v0[j] + m1 * (float)v1[j] + m2 * (float)v2[j];
    }
    bf16x8 o;
#pragma unroll
    for (int j = 0; j < 8; j++) o[j] = (bf16_t)a[j];
    *((bf16x8*)(out + (size_t)seg * HDIM) + l) = o;
}

__global__ __launch_bounds__(256) void segsum_b16(const bf16_t* __restrict__ X,
                                                  const int* __restrict__ rowptr,
                                                  const int* __restrict__ gat,
                                                  bf16_t* __restrict__ out, int nseg) {
    const int seg = (blockIdx.x * 256 + threadIdx.x) >> 4;
    if (seg >= nseg) return;
    const int l = threadIdx.x & 15;
    const bf16x8* __restrict__ Xv = (const bf16x8*)X;
    float a[8];
#pragma unroll
    for (int j = 0; j < 8; j++) a[j] = 0.f;
    const int s0 = rowptr[seg], s1 = rowptr[seg + 1];
    int e = s0;
    for (; e + 4 <= s1; e += 4) {
        int g0 = gat[e], g1 = gat[e + 1], g2 = gat[e + 2], g3 = gat[e + 3];
        bf16x8 v0 = Xv[(size_t)g0 * 16 + l];
        bf16x8 v1 = Xv[(size_t)g1 * 16 + l];
        bf16x8 v2 = Xv[(size_t)g2 * 16 + l];
        bf16x8 v3 = Xv[(size_t)g3 * 16 + l];
#pragma unroll
        for (int j = 0; j < 8; j++)
            a[j] += (float)v0[j] + (float)v1[j] + (float)v2[j] + (float)v3[j];
    }
    const int rem = s1 - e;
    if (rem > 0) {
        int g0 = gat[e];
        int g1 = gat[e + (rem > 1 ? 1 : 0)];
        int g2 = gat[e + (rem > 2 ? 2 : 0)];
        bf16x8 v0 = Xv[(size_t)g0 * 16 + l];
        bf16x8 v1 = Xv[(size_t)g1 * 16 + l];
        bf16x8 v2 = Xv[(size_t)g2 * 16 + l];
        const float m1 = rem > 1 ? 1.f : 0.f;
        const float m2 = rem > 2 ? 1.f : 0.f;
#pragma unroll
        for (int j = 0; j < 8; j++)
            a[j] += (float)v0[j] + m1 * (float)v1[j] + m2 * (float)v2[j];
    }
    bf16x8 o;
#pragma unroll
    for (int j = 0; j < 8; j++) o[j] = (bf16_t)a[j];
    *((bf16x8*)(out + (size_t)seg * HDIM) + l) = o;
}

// ---------------------------------------------------------------------------
// BN finalize
// ---------------------------------------------------------------------------
__global__ void bn_finalize(const float* __restrict__ cs, const float* __restrict__ cs2,
                            const float* __restrict__ g, const float* __restrict__ b,
                            float* __restrict__ scale, float* __restrict__ shift,
                            int C, float invN) {
    int c = blockIdx.x * blockDim.x + threadIdx.x;
    if (c >= C) return;
    float m = cs[c] * invN;
    float v = cs2[c] * invN - m * m;
    float sc = g[c] * rsqrtf(v + 1e-5f);
    scale[c] = sc;
    shift[c] = b[c] - m * sc;
}

// ---------------------------------------------------------------------------
// Register-resident-weight persistent GEMM (BN stats pass only:
// flags 4|8 = column stats, no store).
// flags: 1 relu, 2 accumulate, 4 column stats, 8 no-store.
// ---------------------------------------------------------------------------
template <int K, int NC>
__global__ __launch_bounds__(256, 3) void gemm_reg(
    const bf16_t* __restrict__ Ab,
    const float* __restrict__ bnScale, const float* __restrict__ bnShift,
    const bf16_t* __restrict__ Wt, const float* __restrict__ bias,
    int M,
    bf16_t* __restrict__ outB, float* __restrict__ outF,
    float* __restrict__ colsum, float* __restrict__ colsumsq,
    int bnfold, int flags) {
    constexpr int NKS = K / 32;       // k-steps
    constexpr int SLICE = NC / 4;     // cols per wave
    constexpr int NNI = SLICE / 16;   // n-frags per wave
    const int w = threadIdx.x >> 6, lane = threadIdx.x & 63;
    const int q = lane >> 4, lm = lane & 15;
    const int c0 = w * SLICE;

    bf16x8 bfr[NNI][NKS];
#pragma unroll
    for (int ni = 0; ni < NNI; ni++) {
        const bf16_t* bp = Wt + (size_t)(c0 + ni * 16 + lm) * K + q * 8;
#pragma unroll
        for (int ks = 0; ks < NKS; ks++)
            bfr[ni][ks] = *(const bf16x8*)(bp + ks * 32);
    }
    const bool doRelu = (flags & 1), doAccum = (flags & 2), doStats = (flags & 4);
    const bool doStore = !(flags & 8);
    float bv[NNI];
#pragma unroll
    for (int ni = 0; ni < NNI; ni++) bv[ni] = bias[c0 + ni * 16 + lm];
    float st1[NNI], st2[NNI];
#pragma unroll
    for (int ni = 0; ni < NNI; ni++) { st1[ni] = 0.f; st2[ni] = 0.f; }

    const int nTiles = (M + 31) >> 5;
    for (int t = blockIdx.x; t < nTiles; t += gridDim.x) {
        const int row0 = t << 5;
        bf16x8 af[2][NKS];
#pragma unroll
        for (int mi = 0; mi < 2; mi++) {
            int gr = row0 + mi * 16 + lm;
            if (gr > M - 1) gr = M - 1;
            const bf16_t* ap = Ab + (size_t)gr * K + q * 8;
#pragma unroll
            for (int ks = 0; ks < NKS; ks++)
                af[mi][ks] = *(const bf16x8*)(ap + ks * 32);
        }
        if (bnfold) {
#pragma unroll
            for (int ks = 0; ks < NKS; ks++) {
                const int kk = ks * 32 + q * 8;
                f32x4 s0 = ((const f32x4*)(bnScale + kk))[0];
                f32x4 s1v = ((const f32x4*)(bnScale + kk))[1];
                f32x4 h0 = ((const f32x4*)(bnShift + kk))[0];
                f32x4 h1 = ((const f32x4*)(bnShift + kk))[1];
                float sc8[8] = {s0[0], s0[1], s0[2], s0[3], s1v[0], s1v[1], s1v[2], s1v[3]};
                float sh8[8] = {h0[0], h0[1], h0[2], h0[3], h1[0], h1[1], h1[2], h1[3]};
#pragma unroll
                for (int mi = 0; mi < 2; mi++)
#pragma unroll
                    for (int j = 0; j < 8; j++) {
                        float f = fmaxf((float)af[mi][ks][j] * sc8[j] + sh8[j], 0.f);
                        af[mi][ks][j] = (bf16_t)f;
                    }
            }
        }
        f32x4 acc[2][NNI];
#pragma unroll
        for (int a = 0; a < 2; a++)
#pragma unroll
            for (int b = 0; b < NNI; b++) acc[a][b] = f32x4{0.f, 0.f, 0.f, 0.f};
#pragma unroll
        for (int ks = 0; ks < NKS; ks++)
#pragma unroll
            for (int ni = 0; ni < NNI; ni++) {
                acc[0][ni] = __builtin_amdgcn_mfma_f32_16x16x32_bf16(
                    af[0][ks], bfr[ni][ks], acc[0][ni], 0, 0, 0);
                acc[1][ni] = __builtin_amdgcn_mfma_f32_16x16x32_bf16(
                    af[1][ks], bfr[ni][ks], acc[1][ni], 0, 0, 0);
            }
#pragma unroll
        for (int ni = 0; ni < NNI; ni++) {
            const int col = c0 + ni * 16 + lm;
#pragma unroll
            for (int mi = 0; mi < 2; mi++) {
#pragma unroll
                for (int r = 0; r < 4; r++) {
                    const int row = row0 + mi * 16 + q * 4 + r;
                    if (row < M) {
                        float v = acc[mi][ni][r] + bv[ni];
                        if (doStats) { st1[ni] += v; st2[ni] += v * v; }
                        if (doRelu) v = fmaxf(v, 0.f);
                        if (doStore) {
                            const size_t o = (size_t)row * NC + col;
                            if (outF) {
                                outF[o] = v;
                            } else {
                                if (doAccum) v += (float)outB[o];
                                outB[o] = (bf16_t)v;
                            }
                        }
                    }
                }
            }
        }
    }
    if (doStats) {
#pragma unroll
        for (int ni = 0; ni < NNI; ni++) {
            float s1 = st1[ni], s2 = st2[ni];
            s1 += __shfl_xor(s1, 16);
            s1 += __shfl_xor(s1, 32);
            s2 += __shfl_xor(s2, 16);
            s2 += __shfl_xor(s2, 32);
            if (q == 0) {
                atomicAdd(&colsum[c0 + ni * 16 + lm], s1);
                atomicAdd(&colsumsq[c0 + ni * 16 + lm], s2);
            }
        }
    }
}

// ---------------------------------------------------------------------------
// Fused MLP: out = relu((A@W1+b1)[*bnScale+bnShift]) @ W2 + b2
// K1=128, H2=256, NO=128. 4 waves/block. Both weight slices register-resident
// (64+64 VGPRs/wave). The 32x256 bf16 h-tile goes through double-buffered,
// XOR-swizzled LDS (1 barrier/tile). flags: 1 accumulate (bf16 RMW on
// outB), 2 fp32 store to outF.
// (round-2 proven body; the round-3 register prefetch caused L2 RMW write
//  amplification and was reverted)
// ---------------------------------------------------------------------------
__global__ __launch_bounds__(256, 2) void fused_mlp(
    const bf16_t* __restrict__ Ab,
    const bf16_t* __restrict__ Wt1, const float* __restrict__ b1,
    const float* __restrict__ bnS, const float* __restrict__ bnH,
    const bf16_t* __restrict__ Wt2, const float* __restrict__ b2,
    int M,
    bf16_t* __restrict__ outB, float* __restrict__ outF,
    int bnfold, int flags) {
    __shared__ char hs[2][32 * 512];  // 2 x (32 rows x 256 bf16)
    const int w = threadIdx.x >> 6, lane = threadIdx.x & 63;
    const int q = lane >> 4, lm = lane & 15;
    const int c0h = w * 64;   // wave's H2-column slice
    const int c0o = w * 32;   // wave's out-column slice

    // resident W1 slice: 4 n-frags x 4 k-steps = 64 VGPRs
    bf16x8 bfr1[4][4];
#pragma unroll
    for (int ni = 0; ni < 4; ni++) {
        const bf16_t* bp = Wt1 + (size_t)(c0h + ni * 16 + lm) * 128 + q * 8;
#pragma unroll
        for (int ks = 0; ks < 4; ks++) bfr1[ni][ks] = *(const bf16x8*)(bp + ks * 32);
    }
    // resident W2 slice: 2 n-frags x 8 k-steps = 64 VGPRs
    bf16x8 bfr2[2][8];
#pragma unroll
    for (int ni = 0; ni < 2; ni++) {
        const bf16_t* bp = Wt2 + (size_t)(c0o + ni * 16 + lm) * 256 + q * 8;
#pragma unroll
        for (int ks = 0; ks < 8; ks++) bfr2[ni][ks] = *(const bf16x8*)(bp + ks * 32);
    }
    float bv1[4], bsc[4], bsh[4];
#pragma unroll
    for (int ni = 0; ni < 4; ni++) {
        const int c = c0h + ni * 16 + lm;
        bv1[ni] = b1[c];
        bsc[ni] = bnfold ? bnS[c] : 1.f;
        bsh[ni] = bnfold ? bnH[c] : 0.f;
    }
    float bv2[2];
#pragma unroll
    for (int ni = 0; ni < 2; ni++) bv2[ni] = b2[c0o + ni * 16 + lm];

    const bool doAccum = (flags & 1), f32out = (flags & 2);
    const int nTiles = (M + 31) >> 5;
    int buf = 0;
    for (int t = blockIdx.x; t < nTiles; t += gridDim.x, buf ^= 1) {
        const int row0 = t << 5;
        char* hb = hs[buf];
        // ---- GEMM1: A (global) x W1 (regs) ----
        bf16x8 af[2][4];
#pragma unroll
        for (int mi = 0; mi < 2; mi++) {
            int gr = row0 + mi * 16 + lm;
            if (gr > M - 1) gr = M - 1;  // clamp; stores guarded below
            const bf16_t* ap = Ab + (size_t)gr * 128 + q * 8;
#pragma unroll
            for (int ks = 0; ks < 4; ks++) af[mi][ks] = *(const bf16x8*)(ap + ks * 32);
        }
        f32x4 acc1[2][4];
#pragma unroll
        for (int a = 0; a < 2; a++)
#pragma unroll
            for (int b = 0; b < 4; b++) acc1[a][b] = f32x4{0.f, 0.f, 0.f, 0.f};
#pragma unroll
        for (int ks = 0; ks < 4; ks++)
#pragma unroll
            for (int ni = 0; ni < 4; ni++) {
                acc1[0][ni] = __builtin_amdgcn_mfma_f32_16x16x32_bf16(
                    af[0][ks], bfr1[ni][ks], acc1[0][ni], 0, 0, 0);
                acc1[1][ni] = __builtin_amdgcn_mfma_f32_16x16x32_bf16(
                    af[1][ks], bfr1[ni][ks], acc1[1][ni], 0, 0, 0);
            }
        // ---- mid epilogue: bias (+BN fold) + relu -> swizzled LDS ----
#pragma unroll
        for (int ni = 0; ni < 4; ni++) {
            const int colb = (c0h + ni * 16 + lm) * 2;
#pragma unroll
            for (int mi = 0; mi < 2; mi++)
#pragma unroll
                for (int r = 0; r < 4; r++) {
                    const int row = mi * 16 + q * 4 + r;
                    float v = (acc1[mi][ni][r] + bv1[ni]) * bsc[ni] + bsh[ni];
                    v = fmaxf(v, 0.f);
                    const int swz = ((row & 7) << 4) ^ ((row & 8) << 2);
                    *(bf16_t*)(hb + (row << 9) + (colb ^ swz)) = (bf16_t)v;
                }
        }
        __syncthreads();
        // ---- GEMM2: h (LDS) x W2 (regs) ----
        f32x4 acc2[2][2];
#pragma unroll
        for (int a = 0; a < 2; a++)
#pragma unroll
            for (int b = 0; b < 2; b++) acc2[a][b] = f32x4{0.f, 0.f, 0.f, 0.f};
#pragma unroll
        for (int ks = 0; ks < 8; ks++) {
            const int ko = ks * 64 + q * 16;
            const int r0 = lm, r1 = lm + 16;
            const int s0 = ((r0 & 7) << 4) ^ ((r0 & 8) << 2);
            const int s1 = ((r1 & 7) << 4) ^ ((r1 & 8) << 2);
            bf16x8 a0 = *(const bf16x8*)(hb + (r0 << 9) + (ko ^ s0));
            bf16x8 a1 = *(const bf16x8*)(hb + (r1 << 9) + (ko ^ s1));
#pragma unroll
            for (int ni = 0; ni < 2; ni++) {
                acc2[0][ni] = __builtin_amdgcn_mfma_f32_16x16x32_bf16(
                    a0, bfr2[ni][ks], acc2[0][ni], 0, 0, 0);
                acc2[1][ni] = __builtin_amdgcn_mfma_f32_16x16x32_bf16(
                    a1, bfr2[ni][ks], acc2[1][ni], 0, 0, 0);
            }
        }
        // ---- final epilogue ----
#pragma unroll
        for (int ni = 0; ni < 2; ni++) {
            const int col = c0o + ni * 16 + lm;
#pragma unroll
            for (int mi = 0; mi < 2; mi++)
#pragma unroll
                for (int r = 0; r < 4; r++) {
                    const int row = row0 + mi * 16 + q * 4 + r;
                    if (row < M) {
                        float v = acc2[mi][ni][r] + bv2[ni];
                        const size_t o = (size_t)row * 128 + col;
                        if (f32out) {
                            outF[o] = v;
                        } else {
                            if (doAccum) v += (float)outB[o];
                            outB[o] = (bf16_t)v;
                        }
                    }
                }
        }
        // no trailing barrier: next tile writes the other LDS buffer; the
        // barrier inside iteration t+1 orders read(t) before write(t+2).
    }
}

// ---------------------------------------------------------------------------
extern "C" void kernel_launch(void* const* d_in, const int* in_sizes, int n_in,
                              void* d_out, int out_size, void* d_ws, size_t ws_size,
                              hipStream_t stream) {
    const float* x_in   = (const float*)d_in[0];
    const int*   ei     = (const int*)d_in[1];
    const int*   se0    = (const int*)d_in[2];
    const int*   se1    = (const int*)d_in[3];
    const float* msg_w1 = (const float*)d_in[4];
    const float* msg_b1 = (const float*)d_in[5];
    const float* bn_g   = (const float*)d_in[6];
    const float* bn_b   = (const float*)d_in[7];
    const float* msg_w2 = (const float*)d_in[8];
    const float* msg_b2 = (const float*)d_in[9];
    const float* eps_g  = (const float*)d_in[10];
    const float* n2s_w1 = (const float*)d_in[11];
    const float* n2s_b1 = (const float*)d_in[12];
    const float* n2s_w2 = (const float*)d_in[13];
    const float* n2s_b2 = (const float*)d_in[14];
    const float* s2n_w1 = (const float*)d_in[15];
    const float* s2n_b1 = (const float*)d_in[16];
    const float* s2n_w2 = (const float*)d_in[17];
    const float* s2n_b2 = (const float*)d_in[18];
    const float* out_w1 = (const float*)d_in[19];
    const float* out_b1 = (const float*)d_in[20];
    const float* out_w2 = (const float*)d_in[21];
    const float* out_b2 = (const float*)d_in[22];
    float* out = (float*)d_out;

    char* ws = (char*)d_ws;
    size_t off = 0;
    auto alloc = [&](size_t bytes) -> char* {
        char* p = ws + off;
        off += (bytes + 255) & ~(size_t)255;
        return p;
    };
    bf16_t* xbf   = (bf16_t*)alloc((size_t)N_NODES * HDIM * 2);   // residual x (bf16)
    bf16_t* xcomb = (bf16_t*)alloc((size_t)N_NODES * HDIM * 2);   // gin-comb / s2n msg
    bf16_t* sxsum = (bf16_t*)alloc((size_t)NSUB_G * HDIM * 2);
    bf16_t* sxout = (bf16_t*)alloc((size_t)NSUB_G * HDIM * 2);
    const size_t WSZ = (size_t)HDIM * H2DIM;
    bf16_t* wt_msg1 = (bf16_t*)alloc(NLAYER * WSZ * 2);
    bf16_t* wt_msg2 = (bf16_t*)alloc(NLAYER * WSZ * 2);
    bf16_t* wt_n2s1 = (bf16_t*)alloc(NLAYER * NSUBT * WSZ * 2);
    bf16_t* wt_n2s2 = (bf16_t*)alloc(NLAYER * NSUBT * WSZ * 2);
    bf16_t* wt_s2n1 = (bf16_t*)alloc(NLAYER * NSUBT * WSZ * 2);
    bf16_t* wt_s2n2 = (bf16_t*)alloc(NLAYER * NSUBT * WSZ * 2);
    bf16_t* wt_out1 = (bf16_t*)alloc(WSZ * 2);
    bf16_t* wt_out2 = (bf16_t*)alloc(WSZ * 2);
    float* colsum   = (float*)alloc(H2DIM * 4);
    float* colsumsq = (float*)alloc(H2DIM * 4);
    float* bnscale  = (float*)alloc(H2DIM * 4);
    float* bnshift  = (float*)alloc(H2DIM * 4);
    int* rp_gin   = (int*)alloc((N_NODES + 1) * 4);
    int* gat_gin  = (int*)alloc((size_t)E_EDGES * 4);
    int* rp_n2s0  = (int*)alloc((NSUB_G + 1) * 4);
    int* gat_n2s0 = (int*)alloc((size_t)ESUB_E * 4);
    int* rp_n2s1  = (int*)alloc((NSUB_G + 1) * 4);
    int* gat_n2s1 = (int*)alloc((size_t)ESUB_E * 4);
    int* rp_s2n0  = (int*)alloc((N_NODES + 1) * 4);
    int* gat_s2n0 = (int*)alloc((size_t)ESUB_E * 4);
    int* rp_s2n1  = (int*)alloc((N_NODES + 1) * 4);
    int* gat_s2n1 = (int*)alloc((size_t)ESUB_E * 4);
    int* counts  = (int*)alloc((N_NODES + 1) * 4);
    int* partial = (int*)alloc((size_t)N_NODES * 4);
    int* bsum    = (int*)alloc(512 * 4);
    (void)ws_size; (void)in_sizes; (void)n_in; (void)out_size;

    auto tr = [&](const float* W, bf16_t* Wt, int K, int Nc, int batch) {
        long total = (long)batch * K * Nc;
        int blocks = (int)((total + 255) / 256);
        transpose_w<<<blocks, 256, 0, stream>>>(W, Wt, K, Nc, total);
    };
    tr(msg_w1, wt_msg1, HDIM, H2DIM, NLAYER);
    tr(msg_w2, wt_msg2, H2DIM, HDIM, NLAYER);
    tr(n2s_w1, wt_n2s1, HDIM, H2DIM, NLAYER * NSUBT);
    tr(n2s_w2, wt_n2s2, H2DIM, HDIM, NLAYER * NSUBT);
    tr(s2n_w1, wt_s2n1, HDIM, H2DIM, NLAYER * NSUBT);
    tr(s2n_w2, wt_s2n2, H2DIM, HDIM, NLAYER * NSUBT);
    tr(out_w1, wt_out1, HDIM, H2DIM, 1);
    tr(out_w2, wt_out2, H2DIM, OUTD, 1);

    auto build_csr = [&](const int* idx, const int* gsrc, int nE, int nseg,
                         int* rowptr, int* gat) {
        hipMemsetAsync(counts, 0, (size_t)nseg * 4, stream);
        hist_k<<<(nE + 255) / 256, 256, 0, stream>>>(idx, counts, nE);
        int nb = (nseg + 1023) / 1024;
        scan1_k<<<nb, 256, 0, stream>>>(counts, partial, bsum, nseg);
        scan2_k<<<1, 256, 0, stream>>>(bsum, nb);
        scan3_k<<<(nseg + 255) / 256, 256, 0, stream>>>(partial, bsum, rowptr,
                                                        counts, nseg, nE);
        csr_place<<<(nE + 255) / 256, 256, 0, stream>>>(idx, gsrc, counts, gat, nE);
    };
    const int* src = ei;
    const int* dst = ei + E_EDGES;
    build_csr(dst, src, E_EDGES, N_NODES, rp_gin, gat_gin);
    build_csr(se0 + ESUB_E, se0, ESUB_E, NSUB_G, rp_n2s0, gat_n2s0);
    build_csr(se1 + ESUB_E, se1, ESUB_E, NSUB_G, rp_n2s1, gat_n2s1);
    build_csr(se0, se0 + ESUB_E, ESUB_E, N_NODES, rp_s2n0, gat_s2n0);
    build_csr(se1, se1 + ESUB_E, ESUB_E, N_NODES, rp_s2n1, gat_s2n1);

    {
        long n = (long)N_NODES * HDIM;
        cast_f2b<<<(int)((n / 4 + 255) / 256), 256, 0, stream>>>(x_in, xbf, n);
    }

    // stats-only gemm (K=128, NC=256)
    auto gemmStats = [&](const bf16_t* Ab, const bf16_t* Wt, const float* bias,
                         int M, float* cs, float* cs2) {
        int nt = (M + 31) / 32;
        int g = nt < NBLK ? nt : NBLK;
        gemm_reg<128, 256><<<g, 256, 0, stream>>>(
            Ab, nullptr, nullptr, Wt, bias, M, nullptr, nullptr, cs, cs2, 0, 4 | 8);
    };
    // fused MLP
    auto fmlp = [&](const bf16_t* Ab, const bf16_t* W1t, const float* b1p,
                    const float* bnS, const float* bnH,
                    const bf16_t* W2t, const float* b2p, int M,
                    bf16_t* oB, float* oF, int bnfold, int flags) {
        int nt = (M + 31) / 32;
        int g = nt < FBLK ? nt : FBLK;
        fused_mlp<<<g, 256, 0, stream>>>(Ab, W1t, b1p, bnS, bnH, W2t, b2p, M,
                                         oB, oF, bnfold, flags);
    };

    for (int i = 0; i < NLAYER; i++) {
        // GIN aggregation fused with (1+eps)x combine -> bf16
        segsum_ginb<<<(N_NODES + 15) / 16, 256, 0, stream>>>(
            xbf, eps_g + i, rp_gin, gat_gin, xcomb, N_NODES);
        // pass 1: column stats of h = xcomb@W1+b1 (no h write)
        hipMemsetAsync(colsum, 0, H2DIM * 4, stream);
        hipMemsetAsync(colsumsq, 0, H2DIM * 4, stream);
        gemmStats(xcomb, wt_msg1 + (size_t)i * WSZ, msg_b1 + (size_t)i * H2DIM,
                  N_NODES, colsum, colsumsq);
        bn_finalize<<<1, 256, 0, stream>>>(colsum, colsumsq, bn_g + (size_t)i * H2DIM,
                                           bn_b + (size_t)i * H2DIM, bnscale, bnshift,
                                           H2DIM, 1.0f / N_NODES);
        // pass 2: x = relu(BN(xcomb@W1+b1)) @ W2 + b2 fused
        fmlp(xcomb, wt_msg1 + (size_t)i * WSZ, msg_b1 + (size_t)i * H2DIM,
             bnscale, bnshift,
             wt_msg2 + (size_t)i * WSZ, msg_b2 + (size_t)i * HDIM,
             N_NODES, xbf, nullptr, 1, 0);

        for (int s = 0; s < NSUBT; s++) {
            const int* rp_n2s = (s == 0 ? rp_n2s0 : rp_n2s1);
            const int* gt_n2s = (s == 0 ? gat_n2s0 : gat_n2s1);
            const int* rp_s2n = (s == 0 ? rp_s2n0 : rp_s2n1);
            const int* gt_s2n = (s == 0 ? gat_s2n0 : gat_s2n1);
            const size_t widx = ((size_t)i * NSUBT + s) * WSZ;
            const size_t b1o = ((size_t)i * NSUBT + s) * H2DIM;
            const size_t b2o = ((size_t)i * NSUBT + s) * HDIM;
            // sx = segment_sum(x[row], col)
            segsum_b16<<<(NSUB_G + 15) / 16, 256, 0, stream>>>(
                xbf, rp_n2s, gt_n2s, sxsum, NSUB_G);
            // sx = relu(sx@w1+b1)@w2+b2  (fused)
            fmlp(sxsum, wt_n2s1 + widx, n2s_b1 + b1o, nullptr, nullptr,
                 wt_n2s2 + widx, n2s_b2 + b2o, NSUB_G, sxout, nullptr, 0, 0);
            // msg = segment_sum(sx[col], row)
            segsum_b16<<<(N_NODES + 15) / 16, 256, 0, stream>>>(
                sxout, rp_s2n, gt_s2n, xcomb, N_NODES);
            // x += relu(msg@w1+b1)@w2+b2  (fused, accumulate)
            fmlp(xcomb, wt_s2n1 + widx, s2n_b1 + b1o, nullptr, nullptr,
                 wt_s2n2 + widx, s2n_b2 + b2o, N_NODES, xbf, nullptr, 0, 1);
        }
    }
    // output head (fused, fp32 out)
    fmlp(xbf, wt_out1, out_b1, nullptr, nullptr, wt_out2, out_b2,
         N_NODES, nullptr, out, 0, 2);
}

// Round 5
// 1265.002 us; speedup vs baseline: 1.2571x; 1.1640x over previous
//
#include <hip/hip_runtime.h>
#include <hip/hip_bf16.h>

#define N_NODES 100000
#define E_EDGES 600000
#define HDIM 128
#define H2DIM 256
#define NLAYER 3
#define NSUBT 2
#define NSUB_G 20000
#define ESUB_E 200000
#define OUTD 128
#define NBLK 768  // persistent-GEMM grid: 3 blocks/CU (stats pass)  [round-2 proven]
#define FBLK 512  // fused-MLP grid: 2 blocks/CU  [round-2 proven; 768/1024 regress]

typedef __bf16 bf16_t;
typedef __bf16 bf16x8 __attribute__((ext_vector_type(8)));
typedef __bf16 bf16x4 __attribute__((ext_vector_type(4)));
typedef __bf16 bf16x2 __attribute__((ext_vector_type(2)));
typedef float f32x4 __attribute__((ext_vector_type(4)));
typedef float f32x2 __attribute__((ext_vector_type(2)));

// ---------------------------------------------------------------------------
// Weight transpose: W[k][n] (row-major K x Nc, fp32) -> Wt[n][k] (bf16)
// ---------------------------------------------------------------------------
__global__ __launch_bounds__(256) void transpose_w(const float* __restrict__ W,
                                                   bf16_t* __restrict__ Wt,
                                                   int K, int Nc, long total) {
    long idx = (long)blockIdx.x * 256 + threadIdx.x;
    if (idx >= total) return;
    long kn = (long)K * Nc;
    long b = idx / kn;
    long r = idx - b * kn;
    int k = (int)(r / Nc);
    int n = (int)(r - (long)k * Nc);
    Wt[b * kn + (long)n * K + k] = (bf16_t)W[idx];
}

__global__ __launch_bounds__(256) void cast_f2b(const float* __restrict__ in,
                                                bf16_t* __restrict__ out, long n) {
    long i = ((long)blockIdx.x * 256 + threadIdx.x) * 4;
    if (i >= n) return;
    f32x4 v = *(const f32x4*)(in + i);
    bf16x4 o;
    o[0] = (bf16_t)v[0]; o[1] = (bf16_t)v[1];
    o[2] = (bf16_t)v[2]; o[3] = (bf16_t)v[3];
    *(bf16x4*)(out + i) = o;
}

// ---------------------------------------------------------------------------
// CSR build: histogram -> hierarchical exclusive scan -> placement
// ---------------------------------------------------------------------------
__global__ __launch_bounds__(256) void hist_k(const int* __restrict__ idx,
                                              int* __restrict__ counts, int nE) {
    int e = blockIdx.x * 256 + threadIdx.x;
    if (e < nE) atomicAdd(&counts[idx[e]], 1);
}

__global__ __launch_bounds__(256) void scan1_k(const int* __restrict__ in,
                                               int* __restrict__ out,
                                               int* __restrict__ bsum, int n) {
    __shared__ int tmp[256];
    const int t = threadIdx.x;
    const long base = (long)blockIdx.x * 1024 + (long)t * 4;
    int v[4];
    int s = 0;
#pragma unroll
    for (int j = 0; j < 4; j++) {
        long i = base + j;
        int x = (i < n) ? in[i] : 0;
        v[j] = s;
        s += x;
    }
    tmp[t] = s;
    __syncthreads();
    int inc = s;
    for (int off = 1; off < 256; off <<= 1) {
        int y = (t >= off) ? tmp[t - off] : 0;
        __syncthreads();
        inc += y;
        tmp[t] = inc;
        __syncthreads();
    }
    const int toff = inc - s;
#pragma unroll
    for (int j = 0; j < 4; j++) {
        long i = base + j;
        if (i < n) out[i] = v[j] + toff;
    }
    if (t == 255) bsum[blockIdx.x] = inc;
}

__global__ __launch_bounds__(256) void scan2_k(int* __restrict__ bsum, int nb) {
    __shared__ int tmp[256];
    const int t = threadIdx.x;
    int x = (t < nb) ? bsum[t] : 0;
    tmp[t] = x;
    __syncthreads();
    int inc = x;
    for (int off = 1; off < 256; off <<= 1) {
        int y = (t >= off) ? tmp[t - off] : 0;
        __syncthreads();
        inc += y;
        tmp[t] = inc;
        __syncthreads();
    }
    if (t < nb) bsum[t] = inc - x;
}

__global__ __launch_bounds__(256) void scan3_k(const int* __restrict__ partial,
                                               const int* __restrict__ bsum,
                                               int* __restrict__ rowptr,
                                               int* __restrict__ work,
                                               int n, int total) {
    long i = (long)blockIdx.x * 256 + threadIdx.x;
    if (i < n) {
        int v = partial[i] + bsum[i >> 10];
        rowptr[i] = v;
        work[i] = v;
    }
    if (i == 0) rowptr[n] = total;
}

__global__ __launch_bounds__(256) void csr_place(const int* __restrict__ idx,
                                                 const int* __restrict__ gsrc,
                                                 int* __restrict__ work,
                                                 int* __restrict__ gat, int nE) {
    int e = blockIdx.x * 256 + threadIdx.x;
    if (e < nE) {
        int p = atomicAdd(&work[idx[e]], 1);
        gat[p] = gsrc[e];
    }
}

// ---------------------------------------------------------------------------
// Gather-based segment sums over bf16 features.
// 16-lane group per segment, bf16x8 per lane (16 lanes x 16B = 256B row per
// load instruction). Edge loop unrolled x8 with clamped-index masked loads:
// a degree<=7 segment (73% at mean degree 6) completes in ONE batch of 8
// independent gathers -> 32 rows (8KB) in flight per wave.
// ---------------------------------------------------------------------------
__global__ __launch_bounds__(256) void segsum_ginb(const bf16_t* __restrict__ X,
                                                   const float* __restrict__ epsPtr,
                                                   const int* __restrict__ rowptr,
                                                   const int* __restrict__ gat,
                                                   bf16_t* __restrict__ out, int nseg) {
    const int seg = (blockIdx.x * 256 + threadIdx.x) >> 4;
    if (seg >= nseg) return;
    const int l = threadIdx.x & 15;
    const bf16x8* __restrict__ Xv = (const bf16x8*)X;  // row r at Xv[r*16 + l]
    const float alpha = 1.f + epsPtr[0];
    bf16x8 xv = Xv[(size_t)seg * 16 + l];
    float a[8];
#pragma unroll
    for (int j = 0; j < 8; j++) a[j] = alpha * (float)xv[j];
    const int s0 = rowptr[seg], s1 = rowptr[seg + 1];
    int e = s0;
    for (; e + 8 <= s1; e += 8) {
        int g[8];
#pragma unroll
        for (int u = 0; u < 8; u++) g[u] = gat[e + u];
        bf16x8 v[8];
#pragma unroll
        for (int u = 0; u < 8; u++) v[u] = Xv[(size_t)g[u] * 16 + l];
#pragma unroll
        for (int j = 0; j < 8; j++) {
            float s = 0.f;
#pragma unroll
            for (int u = 0; u < 8; u++) s += (float)v[u][j];
            a[j] += s;
        }
    }
    const int rem = s1 - e;
    if (rem > 0) {
        int g[8];
#pragma unroll
        for (int u = 0; u < 8; u++) g[u] = gat[e + (u < rem ? u : 0)];
        bf16x8 v[8];
#pragma unroll
        for (int u = 0; u < 8; u++) v[u] = Xv[(size_t)g[u] * 16 + l];
        float m[8];
#pragma unroll
        for (int u = 0; u < 8; u++) m[u] = (u < rem) ? 1.f : 0.f;
#pragma unroll
        for (int j = 0; j < 8; j++) {
            float s = 0.f;
#pragma unroll
            for (int u = 0; u < 8; u++) s += m[u] * (float)v[u][j];
            a[j] += s;
        }
    }
    bf16x8 o;
#pragma unroll
    for (int j = 0; j < 8; j++) o[j] = (bf16_t)a[j];
    *((bf16x8*)(out + (size_t)seg * HDIM) + l) = o;
}

__global__ __launch_bounds__(256) void segsum_b16(const bf16_t* __restrict__ X,
                                                  const int* __restrict__ rowptr,
                                                  const int* __restrict__ gat,
                                                  bf16_t* __restrict__ out, int nseg) {
    const int seg = (blockIdx.x * 256 + threadIdx.x) >> 4;
    if (seg >= nseg) return;
    const int l = threadIdx.x & 15;
    const bf16x8* __restrict__ Xv = (const bf16x8*)X;
    float a[8];
#pragma unroll
    for (int j = 0; j < 8; j++) a[j] = 0.f;
    const int s0 = rowptr[seg], s1 = rowptr[seg + 1];
    int e = s0;
    for (; e + 8 <= s1; e += 8) {
        int g[8];
#pragma unroll
        for (int u = 0; u < 8; u++) g[u] = gat[e + u];
        bf16x8 v[8];
#pragma unroll
        for (int u = 0; u < 8; u++) v[u] = Xv[(size_t)g[u] * 16 + l];
#pragma unroll
        for (int j = 0; j < 8; j++) {
            float s = 0.f;
#pragma unroll
            for (int u = 0; u < 8; u++) s += (float)v[u][j];
            a[j] += s;
        }
    }
    const int rem = s1 - e;
    if (rem > 0) {
        int g[8];
#pragma unroll
        for (int u = 0; u < 8; u++) g[u] = gat[e + (u < rem ? u : 0)];
        bf16x8 v[8];
#pragma unroll
        for (int u = 0; u < 8; u++) v[u] = Xv[(size_t)g[u] * 16 + l];
        float m[8];
#pragma unroll
        for (int u = 0; u < 8; u++) m[u] = (u < rem) ? 1.f : 0.f;
#pragma unroll
        for (int j = 0; j < 8; j++) {
            float s = 0.f;
#pragma unroll
            for (int u = 0; u < 8; u++) s += m[u] * (float)v[u][j];
            a[j] += s;
        }
    }
    bf16x8 o;
#pragma unroll
    for (int j = 0; j < 8; j++) o[j] = (bf16_t)a[j];
    *((bf16x8*)(out + (size_t)seg * HDIM) + l) = o;
}

// ---------------------------------------------------------------------------
// BN finalize
// ---------------------------------------------------------------------------
__global__ void bn_finalize(const float* __restrict__ cs, const float* __restrict__ cs2,
                            const float* __restrict__ g, const float* __restrict__ b,
                            float* __restrict__ scale, float* __restrict__ shift,
                            int C, float invN) {
    int c = blockIdx.x * blockDim.x + threadIdx.x;
    if (c >= C) return;
    float m = cs[c] * invN;
    float v = cs2[c] * invN - m * m;
    float sc = g[c] * rsqrtf(v + 1e-5f);
    scale[c] = sc;
    shift[c] = b[c] - m * sc;
}

// ---------------------------------------------------------------------------
// Register-resident-weight persistent GEMM (BN stats pass only:
// flags 4|8 = column stats, no store).
// flags: 1 relu, 2 accumulate, 4 column stats, 8 no-store.
// ---------------------------------------------------------------------------
template <int K, int NC>
__global__ __launch_bounds__(256, 3) void gemm_reg(
    const bf16_t* __restrict__ Ab,
    const float* __restrict__ bnScale, const float* __restrict__ bnShift,
    const bf16_t* __restrict__ Wt, const float* __restrict__ bias,
    int M,
    bf16_t* __restrict__ outB, float* __restrict__ outF,
    float* __restrict__ colsum, float* __restrict__ colsumsq,
    int bnfold, int flags) {
    constexpr int NKS = K / 32;       // k-steps
    constexpr int SLICE = NC / 4;     // cols per wave
    constexpr int NNI = SLICE / 16;   // n-frags per wave
    const int w = threadIdx.x >> 6, lane = threadIdx.x & 63;
    const int q = lane >> 4, lm = lane & 15;
    const int c0 = w * SLICE;

    bf16x8 bfr[NNI][NKS];
#pragma unroll
    for (int ni = 0; ni < NNI; ni++) {
        const bf16_t* bp = Wt + (size_t)(c0 + ni * 16 + lm) * K + q * 8;
#pragma unroll
        for (int ks = 0; ks < NKS; ks++)
            bfr[ni][ks] = *(const bf16x8*)(bp + ks * 32);
    }
    const bool doRelu = (flags & 1), doAccum = (flags & 2), doStats = (flags & 4);
    const bool doStore = !(flags & 8);
    float bv[NNI];
#pragma unroll
    for (int ni = 0; ni < NNI; ni++) bv[ni] = bias[c0 + ni * 16 + lm];
    float st1[NNI], st2[NNI];
#pragma unroll
    for (int ni = 0; ni < NNI; ni++) { st1[ni] = 0.f; st2[ni] = 0.f; }

    const int nTiles = (M + 31) >> 5;
    for (int t = blockIdx.x; t < nTiles; t += gridDim.x) {
        const int row0 = t << 5;
        bf16x8 af[2][NKS];
#pragma unroll
        for (int mi = 0; mi < 2; mi++) {
            int gr = row0 + mi * 16 + lm;
            if (gr > M - 1) gr = M - 1;
            const bf16_t* ap = Ab + (size_t)gr * K + q * 8;
#pragma unroll
            for (int ks = 0; ks < NKS; ks++)
                af[mi][ks] = *(const bf16x8*)(ap + ks * 32);
        }
        if (bnfold) {
#pragma unroll
            for (int ks = 0; ks < NKS; ks++) {
                const int kk = ks * 32 + q * 8;
                f32x4 s0 = ((const f32x4*)(bnScale + kk))[0];
                f32x4 s1v = ((const f32x4*)(bnScale + kk))[1];
                f32x4 h0 = ((const f32x4*)(bnShift + kk))[0];
                f32x4 h1 = ((const f32x4*)(bnShift + kk))[1];
                float sc8[8] = {s0[0], s0[1], s0[2], s0[3], s1v[0], s1v[1], s1v[2], s1v[3]};
                float sh8[8] = {h0[0], h0[1], h0[2], h0[3], h1[0], h1[1], h1[2], h1[3]};
#pragma unroll
                for (int mi = 0; mi < 2; mi++)
#pragma unroll
                    for (int j = 0; j < 8; j++) {
                        float f = fmaxf((float)af[mi][ks][j] * sc8[j] + sh8[j], 0.f);
                        af[mi][ks][j] = (bf16_t)f;
                    }
            }
        }
        f32x4 acc[2][NNI];
#pragma unroll
        for (int a = 0; a < 2; a++)
#pragma unroll
            for (int b = 0; b < NNI; b++) acc[a][b] = f32x4{0.f, 0.f, 0.f, 0.f};
#pragma unroll
        for (int ks = 0; ks < NKS; ks++)
#pragma unroll
            for (int ni = 0; ni < NNI; ni++) {
                acc[0][ni] = __builtin_amdgcn_mfma_f32_16x16x32_bf16(
                    af[0][ks], bfr[ni][ks], acc[0][ni], 0, 0, 0);
                acc[1][ni] = __builtin_amdgcn_mfma_f32_16x16x32_bf16(
                    af[1][ks], bfr[ni][ks], acc[1][ni], 0, 0, 0);
            }
#pragma unroll
        for (int ni = 0; ni < NNI; ni++) {
            const int col = c0 + ni * 16 + lm;
#pragma unroll
            for (int mi = 0; mi < 2; mi++) {
#pragma unroll
                for (int r = 0; r < 4; r++) {
                    const int row = row0 + mi * 16 + q * 4 + r;
                    if (row < M) {
                        float v = acc[mi][ni][r] + bv[ni];
                        if (doStats) { st1[ni] += v; st2[ni] += v * v; }
                        if (doRelu) v = fmaxf(v, 0.f);
                        if (doStore) {
                            const size_t o = (size_t)row * NC + col;
                            if (outF) {
                                outF[o] = v;
                            } else {
                                if (doAccum) v += (float)outB[o];
                                outB[o] = (bf16_t)v;
                            }
                        }
                    }
                }
            }
        }
    }
    if (doStats) {
#pragma unroll
        for (int ni = 0; ni < NNI; ni++) {
            float s1 = st1[ni], s2 = st2[ni];
            s1 += __shfl_xor(s1, 16);
            s1 += __shfl_xor(s1, 32);
            s2 += __shfl_xor(s2, 16);
            s2 += __shfl_xor(s2, 32);
            if (q == 0) {
                atomicAdd(&colsum[c0 + ni * 16 + lm], s1);
                atomicAdd(&colsumsq[c0 + ni * 16 + lm], s2);
            }
        }
    }
}

// ---------------------------------------------------------------------------
// Fused MLP: out = relu((A@W1+b1)[*bnScale+bnShift]) @ W2 + b2
// K1=128, H2=256, NO=128. 4 waves/block. Both weight slices register-resident
// (64+64 VGPRs/wave). The 32x256 bf16 h-tile goes through double-buffered,
// XOR-swizzled LDS (1 barrier/tile). flags: 1 accumulate (bf16 RMW on
// outB), 2 fp32 store to outF.
// ROUND-2 PROVEN BODY, FBLK=512. Do not change grid (768/1024 measured worse)
// or add register prefetch (measured worse).
// ---------------------------------------------------------------------------
__global__ __launch_bounds__(256, 2) void fused_mlp(
    const bf16_t* __restrict__ Ab,
    const bf16_t* __restrict__ Wt1, const float* __restrict__ b1,
    const float* __restrict__ bnS, const float* __restrict__ bnH,
    const bf16_t* __restrict__ Wt2, const float* __restrict__ b2,
    int M,
    bf16_t* __restrict__ outB, float* __restrict__ outF,
    int bnfold, int flags) {
    __shared__ char hs[2][32 * 512];  // 2 x (32 rows x 256 bf16)
    const int w = threadIdx.x >> 6, lane = threadIdx.x & 63;
    const int q = lane >> 4, lm = lane & 15;
    const int c0h = w * 64;   // wave's H2-column slice
    const int c0o = w * 32;   // wave's out-column slice

    // resident W1 slice: 4 n-frags x 4 k-steps = 64 VGPRs
    bf16x8 bfr1[4][4];
#pragma unroll
    for (int ni = 0; ni < 4; ni++) {
        const bf16_t* bp = Wt1 + (size_t)(c0h + ni * 16 + lm) * 128 + q * 8;
#pragma unroll
        for (int ks = 0; ks < 4; ks++) bfr1[ni][ks] = *(const bf16x8*)(bp + ks * 32);
    }
    // resident W2 slice: 2 n-frags x 8 k-steps = 64 VGPRs
    bf16x8 bfr2[2][8];
#pragma unroll
    for (int ni = 0; ni < 2; ni++) {
        const bf16_t* bp = Wt2 + (size_t)(c0o + ni * 16 + lm) * 256 + q * 8;
#pragma unroll
        for (int ks = 0; ks < 8; ks++) bfr2[ni][ks] = *(const bf16x8*)(bp + ks * 32);
    }
    float bv1[4], bsc[4], bsh[4];
#pragma unroll
    for (int ni = 0; ni < 4; ni++) {
        const int c = c0h + ni * 16 + lm;
        bv1[ni] = b1[c];
        bsc[ni] = bnfold ? bnS[c] : 1.f;
        bsh[ni] = bnfold ? bnH[c] : 0.f;
    }
    float bv2[2];
#pragma unroll
    for (int ni = 0; ni < 2; ni++) bv2[ni] = b2[c0o + ni * 16 + lm];

    const bool doAccum = (flags & 1), f32out = (flags & 2);
    const int nTiles = (M + 31) >> 5;
    int buf = 0;
    for (int t = blockIdx.x; t < nTiles; t += gridDim.x, buf ^= 1) {
        const int row0 = t << 5;
        char* hb = hs[buf];
        // ---- GEMM1: A (global) x W1 (regs) ----
        bf16x8 af[2][4];
#pragma unroll
        for (int mi = 0; mi < 2; mi++) {
            int gr = row0 + mi * 16 + lm;
            if (gr > M - 1) gr = M - 1;  // clamp; stores guarded below
            const bf16_t* ap = Ab + (size_t)gr * 128 + q * 8;
#pragma unroll
            for (int ks = 0; ks < 4; ks++) af[mi][ks] = *(const bf16x8*)(ap + ks * 32);
        }
        f32x4 acc1[2][4];
#pragma unroll
        for (int a = 0; a < 2; a++)
#pragma unroll
            for (int b = 0; b < 4; b++) acc1[a][b] = f32x4{0.f, 0.f, 0.f, 0.f};
#pragma unroll
        for (int ks = 0; ks < 4; ks++)
#pragma unroll
            for (int ni = 0; ni < 4; ni++) {
                acc1[0][ni] = __builtin_amdgcn_mfma_f32_16x16x32_bf16(
                    af[0][ks], bfr1[ni][ks], acc1[0][ni], 0, 0, 0);
                acc1[1][ni] = __builtin_amdgcn_mfma_f32_16x16x32_bf16(
                    af[1][ks], bfr1[ni][ks], acc1[1][ni], 0, 0, 0);
            }
        // ---- mid epilogue: bias (+BN fold) + relu -> swizzled LDS ----
#pragma unroll
        for (int ni = 0; ni < 4; ni++) {
            const int colb = (c0h + ni * 16 + lm) * 2;
#pragma unroll
            for (int mi = 0; mi < 2; mi++)
#pragma unroll
                for (int r = 0; r < 4; r++) {
                    const int row = mi * 16 + q * 4 + r;
                    float v = (acc1[mi][ni][r] + bv1[ni]) * bsc[ni] + bsh[ni];
                    v = fmaxf(v, 0.f);
                    const int swz = ((row & 7) << 4) ^ ((row & 8) << 2);
                    *(bf16_t*)(hb + (row << 9) + (colb ^ swz)) = (bf16_t)v;
                }
        }
        __syncthreads();
        // ---- GEMM2: h (LDS) x W2 (regs) ----
        f32x4 acc2[2][2];
#pragma unroll
        for (int a = 0; a < 2; a++)
#pragma unroll
            for (int b = 0; b < 2; b++) acc2[a][b] = f32x4{0.f, 0.f, 0.f, 0.f};
#pragma unroll
        for (int ks = 0; ks < 8; ks++) {
            const int ko = ks * 64 + q * 16;
            const int r0 = lm, r1 = lm + 16;
            const int s0 = ((r0 & 7) << 4) ^ ((r0 & 8) << 2);
            const int s1 = ((r1 & 7) << 4) ^ ((r1 & 8) << 2);
            bf16x8 a0 = *(const bf16x8*)(hb + (r0 << 9) + (ko ^ s0));
            bf16x8 a1 = *(const bf16x8*)(hb + (r1 << 9) + (ko ^ s1));
#pragma unroll
            for (int ni = 0; ni < 2; ni++) {
                acc2[0][ni] = __builtin_amdgcn_mfma_f32_16x16x32_bf16(
                    a0, bfr2[ni][ks], acc2[0][ni], 0, 0, 0);
                acc2[1][ni] = __builtin_amdgcn_mfma_f32_16x16x32_bf16(
                    a1, bfr2[ni][ks], acc2[1][ni], 0, 0, 0);
            }
        }
        // ---- final epilogue ----
#pragma unroll
        for (int ni = 0; ni < 2; ni++) {
            const int col = c0o + ni * 16 + lm;
#pragma unroll
            for (int mi = 0; mi < 2; mi++)
#pragma unroll
                for (int r = 0; r < 4; r++) {
                    const int row = row0 + mi * 16 + q * 4 + r;
                    if (row < M) {
                        float v = acc2[mi][ni][r] + bv2[ni];
                        const size_t o = (size_t)row * 128 + col;
                        if (f32out) {
                            outF[o] = v;
                        } else {
                            if (doAccum) v += (float)outB[o];
                            outB[o] = (bf16_t)v;
                        }
                    }
                }
        }
        // no trailing barrier: next tile writes the other LDS buffer; the
        // barrier inside iteration t+1 orders read(t) before write(t+2).
    }
}

// ---------------------------------------------------------------------------
extern "C" void kernel_launch(void* const* d_in, const int* in_sizes, int n_in,
                              void* d_out, int out_size, void* d_ws, size_t ws_size,
                              hipStream_t stream) {
    const float* x_in   = (const float*)d_in[0];
    const int*   ei     = (const int*)d_in[1];
    const int*   se0    = (const int*)d_in[2];
    const int*   se1    = (const int*)d_in[3];
    const float* msg_w1 = (const float*)d_in[4];
    const float* msg_b1 = (const float*)d_in[5];
    const float* bn_g   = (const float*)d_in[6];
    const float* bn_b   = (const float*)d_in[7];
    const float* msg_w2 = (const float*)d_in[8];
    const float* msg_b2 = (const float*)d_in[9];
    const float* eps_g  = (const float*)d_in[10];
    const float* n2s_w1 = (const float*)d_in[11];
    const float* n2s_b1 = (const float*)d_in[12];
    const float* n2s_w2 = (const float*)d_in[13];
    const float* n2s_b2 = (const float*)d_in[14];
    const float* s2n_w1 = (const float*)d_in[15];
    const float* s2n_b1 = (const float*)d_in[16];
    const float* s2n_w2 = (const float*)d_in[17];
    const float* s2n_b2 = (const float*)d_in[18];
    const float* out_w1 = (const float*)d_in[19];
    const float* out_b1 = (const float*)d_in[20];
    const float* out_w2 = (const float*)d_in[21];
    const float* out_b2 = (const float*)d_in[22];
    float* out = (float*)d_out;

    char* ws = (char*)d_ws;
    size_t off = 0;
    auto alloc = [&](size_t bytes) -> char* {
        char* p = ws + off;
        off += (bytes + 255) & ~(size_t)255;
        return p;
    };
    bf16_t* xbf   = (bf16_t*)alloc((size_t)N_NODES * HDIM * 2);   // residual x (bf16)
    bf16_t* xcomb = (bf16_t*)alloc((size_t)N_NODES * HDIM * 2);   // gin-comb / s2n msg
    bf16_t* sxsum = (bf16_t*)alloc((size_t)NSUB_G * HDIM * 2);
    bf16_t* sxout = (bf16_t*)alloc((size_t)NSUB_G * HDIM * 2);
    const size_t WSZ = (size_t)HDIM * H2DIM;
    bf16_t* wt_msg1 = (bf16_t*)alloc(NLAYER * WSZ * 2);
    bf16_t* wt_msg2 = (bf16_t*)alloc(NLAYER * WSZ * 2);
    bf16_t* wt_n2s1 = (bf16_t*)alloc(NLAYER * NSUBT * WSZ * 2);
    bf16_t* wt_n2s2 = (bf16_t*)alloc(NLAYER * NSUBT * WSZ * 2);
    bf16_t* wt_s2n1 = (bf16_t*)alloc(NLAYER * NSUBT * WSZ * 2);
    bf16_t* wt_s2n2 = (bf16_t*)alloc(NLAYER * NSUBT * WSZ * 2);
    bf16_t* wt_out1 = (bf16_t*)alloc(WSZ * 2);
    bf16_t* wt_out2 = (bf16_t*)alloc(WSZ * 2);
    float* colsum   = (float*)alloc(H2DIM * 4);
    float* colsumsq = (float*)alloc(H2DIM * 4);
    float* bnscale  = (float*)alloc(H2DIM * 4);
    float* bnshift  = (float*)alloc(H2DIM * 4);
    int* rp_gin   = (int*)alloc((N_NODES + 1) * 4);
    int* gat_gin  = (int*)alloc((size_t)E_EDGES * 4);
    int* rp_n2s0  = (int*)alloc((NSUB_G + 1) * 4);
    int* gat_n2s0 = (int*)alloc((size_t)ESUB_E * 4);
    int* rp_n2s1  = (int*)alloc((NSUB_G + 1) * 4);
    int* gat_n2s1 = (int*)alloc((size_t)ESUB_E * 4);
    int* rp_s2n0  = (int*)alloc((N_NODES + 1) * 4);
    int* gat_s2n0 = (int*)alloc((size_t)ESUB_E * 4);
    int* rp_s2n1  = (int*)alloc((N_NODES + 1) * 4);
    int* gat_s2n1 = (int*)alloc((size_t)ESUB_E * 4);
    int* counts  = (int*)alloc((N_NODES + 1) * 4);
    int* partial = (int*)alloc((size_t)N_NODES * 4);
    int* bsum    = (int*)alloc(512 * 4);
    (void)ws_size; (void)in_sizes; (void)n_in; (void)out_size;

    auto tr = [&](const float* W, bf16_t* Wt, int K, int Nc, int batch) {
        long total = (long)batch * K * Nc;
        int blocks = (int)((total + 255) / 256);
        transpose_w<<<blocks, 256, 0, stream>>>(W, Wt, K, Nc, total);
    };
    tr(msg_w1, wt_msg1, HDIM, H2DIM, NLAYER);
    tr(msg_w2, wt_msg2, H2DIM, HDIM, NLAYER);
    tr(n2s_w1, wt_n2s1, HDIM, H2DIM, NLAYER * NSUBT);
    tr(n2s_w2, wt_n2s2, H2DIM, HDIM, NLAYER * NSUBT);
    tr(s2n_w1, wt_s2n1, HDIM, H2DIM, NLAYER * NSUBT);
    tr(s2n_w2, wt_s2n2, H2DIM, HDIM, NLAYER * NSUBT);
    tr(out_w1, wt_out1, HDIM, H2DIM, 1);
    tr(out_w2, wt_out2, H2DIM, OUTD, 1);

    auto build_csr = [&](const int* idx, const int* gsrc, int nE, int nseg,
                         int* rowptr, int* gat) {
        hipMemsetAsync(counts, 0, (size_t)nseg * 4, stream);
        hist_k<<<(nE + 255) / 256, 256, 0, stream>>>(idx, counts, nE);
        int nb = (nseg + 1023) / 1024;
        scan1_k<<<nb, 256, 0, stream>>>(counts, partial, bsum, nseg);
        scan2_k<<<1, 256, 0, stream>>>(bsum, nb);
        scan3_k<<<(nseg + 255) / 256, 256, 0, stream>>>(partial, bsum, rowptr,
                                                        counts, nseg, nE);
        csr_place<<<(nE + 255) / 256, 256, 0, stream>>>(idx, gsrc, counts, gat, nE);
    };
    const int* src = ei;
    const int* dst = ei + E_EDGES;
    build_csr(dst, src, E_EDGES, N_NODES, rp_gin, gat_gin);
    build_csr(se0 + ESUB_E, se0, ESUB_E, NSUB_G, rp_n2s0, gat_n2s0);
    build_csr(se1 + ESUB_E, se1, ESUB_E, NSUB_G, rp_n2s1, gat_n2s1);
    build_csr(se0, se0 + ESUB_E, ESUB_E, N_NODES, rp_s2n0, gat_s2n0);
    build_csr(se1, se1 + ESUB_E, ESUB_E, N_NODES, rp_s2n1, gat_s2n1);

    {
        long n = (long)N_NODES * HDIM;
        cast_f2b<<<(int)((n / 4 + 255) / 256), 256, 0, stream>>>(x_in, xbf, n);
    }

    // stats-only gemm (K=128, NC=256)
    auto gemmStats = [&](const bf16_t* Ab, const bf16_t* Wt, const float* bias,
                         int M, float* cs, float* cs2) {
        int nt = (M + 31) / 32;
        int g = nt < NBLK ? nt : NBLK;
        gemm_reg<128, 256><<<g, 256, 0, stream>>>(
            Ab, nullptr, nullptr, Wt, bias, M, nullptr, nullptr, cs, cs2, 0, 4 | 8);
    };
    // fused MLP
    auto fmlp = [&](const bf16_t* Ab, const bf16_t* W1t, const float* b1p,
                    const float* bnS, const float* bnH,
                    const bf16_t* W2t, const float* b2p, int M,
                    bf16_t* oB, float* oF, int bnfold, int flags) {
        int nt = (M + 31) / 32;
        int g = nt < FBLK ? nt : FBLK;
        fused_mlp<<<g, 256, 0, stream>>>(Ab, W1t, b1p, bnS, bnH, W2t, b2p, M,
                                         oB, oF, bnfold, flags);
    };

    for (int i = 0; i < NLAYER; i++) {
        // GIN aggregation fused with (1+eps)x combine -> bf16
        segsum_ginb<<<(N_NODES + 15) / 16, 256, 0, stream>>>(
            xbf, eps_g + i, rp_gin, gat_gin, xcomb, N_NODES);
        // pass 1: column stats of h = xcomb@W1+b1 (no h write)
        hipMemsetAsync(colsum, 0, H2DIM * 4, stream);
        hipMemsetAsync(colsumsq, 0, H2DIM * 4, stream);
        gemmStats(xcomb, wt_msg1 + (size_t)i * WSZ, msg_b1 + (size_t)i * H2DIM,
                  N_NODES, colsum, colsumsq);
        bn_finalize<<<1, 256, 0, stream>>>(colsum, colsumsq, bn_g + (size_t)i * H2DIM,
                                           bn_b + (size_t)i * H2DIM, bnscale, bnshift,
                                           H2DIM, 1.0f / N_NODES);
        // pass 2: x = relu(BN(xcomb@W1+b1)) @ W2 + b2 fused
        fmlp(xcomb, wt_msg1 + (size_t)i * WSZ, msg_b1 + (size_t)i * H2DIM,
             bnscale, bnshift,
             wt_msg2 + (size_t)i * WSZ, msg_b2 + (size_t)i * HDIM,
             N_NODES, xbf, nullptr, 1, 0);

        for (int s = 0; s < NSUBT; s++) {
            const int* rp_n2s = (s == 0 ? rp_n2s0 : rp_n2s1);
            const int* gt_n2s = (s == 0 ? gat_n2s0 : gat_n2s1);
            const int* rp_s2n = (s == 0 ? rp_s2n0 : rp_s2n1);
            const int* gt_s2n = (s == 0 ? gat_s2n0 : gat_s2n1);
            const size_t widx = ((size_t)i * NSUBT + s) * WSZ;
            const size_t b1o = ((size_t)i * NSUBT + s) * H2DIM;
            const size_t b2o = ((size_t)i * NSUBT + s) * HDIM;
            // sx = segment_sum(x[row], col)
            segsum_b16<<<(NSUB_G + 15) / 16, 256, 0, stream>>>(
                xbf, rp_n2s, gt_n2s, sxsum, NSUB_G);
            // sx = relu(sx@w1+b1)@w2+b2  (fused)
            fmlp(sxsum, wt_n2s1 + widx, n2s_b1 + b1o, nullptr, nullptr,
                 wt_n2s2 + widx, n2s_b2 + b2o, NSUB_G, sxout, nullptr, 0, 0);
            // msg = segment_sum(sx[col], row)
            segsum_b16<<<(N_NODES + 15) / 16, 256, 0, stream>>>(
                sxout, rp_s2n, gt_s2n, xcomb, N_NODES);
            // x += relu(msg@w1+b1)@w2+b2  (fused, accumulate)
            fmlp(xcomb, wt_s2n1 + widx, s2n_b1 + b1o, nullptr, nullptr,
                 wt_s2n2 + widx, s2n_b2 + b2o, N_NODES, xbf, nullptr, 0, 1);
        }
    }
    // output head (fused, fp32 out)
    fmlp(xbf, wt_out1, out_b1, nullptr, nullptr, wt_out2, out_b2,
         N_NODES, nullptr, out, 0, 2);
}

// Round 6
// 1133.672 us; speedup vs baseline: 1.4028x; 1.1158x over previous
//
#include <hip/hip_runtime.h>
#include <hip/hip_bf16.h>

#define N_NODES 100000
#define E_EDGES 600000
#define HDIM 128
#define H2DIM 256
#define NLAYER 3
#define NSUBT 2
#define NSUB_G 20000
#define ESUB_E 200000
#define OUTD 128
#define NBLK 768  // persistent-GEMM grid: 3 blocks/CU (stats pass)  [proven]
#define FBLK 512  // fused-MLP grid: 2 blocks/CU  [proven; 768/1024 regress]

typedef __bf16 bf16_t;
typedef __bf16 bf16x8 __attribute__((ext_vector_type(8)));
typedef __bf16 bf16x4 __attribute__((ext_vector_type(4)));
typedef __bf16 bf16x2 __attribute__((ext_vector_type(2)));
typedef float f32x4 __attribute__((ext_vector_type(4)));
typedef float f32x2 __attribute__((ext_vector_type(2)));

// ---------------------------------------------------------------------------
// Weight transpose: W[k][n] (row-major K x Nc, fp32) -> Wt[n][k] (bf16)
// ---------------------------------------------------------------------------
__global__ __launch_bounds__(256) void transpose_w(const float* __restrict__ W,
                                                   bf16_t* __restrict__ Wt,
                                                   int K, int Nc, long total) {
    long idx = (long)blockIdx.x * 256 + threadIdx.x;
    if (idx >= total) return;
    long kn = (long)K * Nc;
    long b = idx / kn;
    long r = idx - b * kn;
    int k = (int)(r / Nc);
    int n = (int)(r - (long)k * Nc);
    Wt[b * kn + (long)n * K + k] = (bf16_t)W[idx];
}

__global__ __launch_bounds__(256) void cast_f2b(const float* __restrict__ in,
                                                bf16_t* __restrict__ out, long n) {
    long i = ((long)blockIdx.x * 256 + threadIdx.x) * 4;
    if (i >= n) return;
    f32x4 v = *(const f32x4*)(in + i);
    bf16x4 o;
    o[0] = (bf16_t)v[0]; o[1] = (bf16_t)v[1];
    o[2] = (bf16_t)v[2]; o[3] = (bf16_t)v[3];
    *(bf16x4*)(out + i) = o;
}

// ---------------------------------------------------------------------------
// CSR build: histogram -> hierarchical exclusive scan -> placement
// ---------------------------------------------------------------------------
__global__ __launch_bounds__(256) void hist_k(const int* __restrict__ idx,
                                              int* __restrict__ counts, int nE) {
    int e = blockIdx.x * 256 + threadIdx.x;
    if (e < nE) atomicAdd(&counts[idx[e]], 1);
}

__global__ __launch_bounds__(256) void scan1_k(const int* __restrict__ in,
                                               int* __restrict__ out,
                                               int* __restrict__ bsum, int n) {
    __shared__ int tmp[256];
    const int t = threadIdx.x;
    const long base = (long)blockIdx.x * 1024 + (long)t * 4;
    int v[4];
    int s = 0;
#pragma unroll
    for (int j = 0; j < 4; j++) {
        long i = base + j;
        int x = (i < n) ? in[i] : 0;
        v[j] = s;
        s += x;
    }
    tmp[t] = s;
    __syncthreads();
    int inc = s;
    for (int off = 1; off < 256; off <<= 1) {
        int y = (t >= off) ? tmp[t - off] : 0;
        __syncthreads();
        inc += y;
        tmp[t] = inc;
        __syncthreads();
    }
    const int toff = inc - s;
#pragma unroll
    for (int j = 0; j < 4; j++) {
        long i = base + j;
        if (i < n) out[i] = v[j] + toff;
    }
    if (t == 255) bsum[blockIdx.x] = inc;
}

__global__ __launch_bounds__(256) void scan2_k(int* __restrict__ bsum, int nb) {
    __shared__ int tmp[256];
    const int t = threadIdx.x;
    int x = (t < nb) ? bsum[t] : 0;
    tmp[t] = x;
    __syncthreads();
    int inc = x;
    for (int off = 1; off < 256; off <<= 1) {
        int y = (t >= off) ? tmp[t - off] : 0;
        __syncthreads();
        inc += y;
        tmp[t] = inc;
        __syncthreads();
    }
    if (t < nb) bsum[t] = inc - x;
}

__global__ __launch_bounds__(256) void scan3_k(const int* __restrict__ partial,
                                               const int* __restrict__ bsum,
                                               int* __restrict__ rowptr,
                                               int* __restrict__ work,
                                               int n, int total) {
    long i = (long)blockIdx.x * 256 + threadIdx.x;
    if (i < n) {
        int v = partial[i] + bsum[i >> 10];
        rowptr[i] = v;
        work[i] = v;
    }
    if (i == 0) rowptr[n] = total;
}

__global__ __launch_bounds__(256) void csr_place(const int* __restrict__ idx,
                                                 const int* __restrict__ gsrc,
                                                 int* __restrict__ work,
                                                 int* __restrict__ gat, int nE) {
    int e = blockIdx.x * 256 + threadIdx.x;
    if (e < nE) {
        int p = atomicAdd(&work[idx[e]], 1);
        gat[p] = gsrc[e];
    }
}

// ---------------------------------------------------------------------------
// Gather-based segment sums over bf16 features.
// 16-lane group per segment, bf16x8 per lane; edge loop unrolled x8.
// ---------------------------------------------------------------------------
__global__ __launch_bounds__(256) void segsum_ginb(const bf16_t* __restrict__ X,
                                                   const float* __restrict__ epsPtr,
                                                   const int* __restrict__ rowptr,
                                                   const int* __restrict__ gat,
                                                   bf16_t* __restrict__ out, int nseg) {
    const int seg = (blockIdx.x * 256 + threadIdx.x) >> 4;
    if (seg >= nseg) return;
    const int l = threadIdx.x & 15;
    const bf16x8* __restrict__ Xv = (const bf16x8*)X;  // row r at Xv[r*16 + l]
    const float alpha = 1.f + epsPtr[0];
    bf16x8 xv = Xv[(size_t)seg * 16 + l];
    float a[8];
#pragma unroll
    for (int j = 0; j < 8; j++) a[j] = alpha * (float)xv[j];
    const int s0 = rowptr[seg], s1 = rowptr[seg + 1];
    int e = s0;
    for (; e + 8 <= s1; e += 8) {
        int g[8];
#pragma unroll
        for (int u = 0; u < 8; u++) g[u] = gat[e + u];
        bf16x8 v[8];
#pragma unroll
        for (int u = 0; u < 8; u++) v[u] = Xv[(size_t)g[u] * 16 + l];
#pragma unroll
        for (int j = 0; j < 8; j++) {
            float s = 0.f;
#pragma unroll
            for (int u = 0; u < 8; u++) s += (float)v[u][j];
            a[j] += s;
        }
    }
    const int rem = s1 - e;
    if (rem > 0) {
        int g[8];
#pragma unroll
        for (int u = 0; u < 8; u++) g[u] = gat[e + (u < rem ? u : 0)];
        bf16x8 v[8];
#pragma unroll
        for (int u = 0; u < 8; u++) v[u] = Xv[(size_t)g[u] * 16 + l];
        float m[8];
#pragma unroll
        for (int u = 0; u < 8; u++) m[u] = (u < rem) ? 1.f : 0.f;
#pragma unroll
        for (int j = 0; j < 8; j++) {
            float s = 0.f;
#pragma unroll
            for (int u = 0; u < 8; u++) s += m[u] * (float)v[u][j];
            a[j] += s;
        }
    }
    bf16x8 o;
#pragma unroll
    for (int j = 0; j < 8; j++) o[j] = (bf16_t)a[j];
    *((bf16x8*)(out + (size_t)seg * HDIM) + l) = o;
}

__global__ __launch_bounds__(256) void segsum_b16(const bf16_t* __restrict__ X,
                                                  const int* __restrict__ rowptr,
                                                  const int* __restrict__ gat,
                                                  bf16_t* __restrict__ out, int nseg) {
    const int seg = (blockIdx.x * 256 + threadIdx.x) >> 4;
    if (seg >= nseg) return;
    const int l = threadIdx.x & 15;
    const bf16x8* __restrict__ Xv = (const bf16x8*)X;
    float a[8];
#pragma unroll
    for (int j = 0; j < 8; j++) a[j] = 0.f;
    const int s0 = rowptr[seg], s1 = rowptr[seg + 1];
    int e = s0;
    for (; e + 8 <= s1; e += 8) {
        int g[8];
#pragma unroll
        for (int u = 0; u < 8; u++) g[u] = gat[e + u];
        bf16x8 v[8];
#pragma unroll
        for (int u = 0; u < 8; u++) v[u] = Xv[(size_t)g[u] * 16 + l];
#pragma unroll
        for (int j = 0; j < 8; j++) {
            float s = 0.f;
#pragma unroll
            for (int u = 0; u < 8; u++) s += (float)v[u][j];
            a[j] += s;
        }
    }
    const int rem = s1 - e;
    if (rem > 0) {
        int g[8];
#pragma unroll
        for (int u = 0; u < 8; u++) g[u] = gat[e + (u < rem ? u : 0)];
        bf16x8 v[8];
#pragma unroll
        for (int u = 0; u < 8; u++) v[u] = Xv[(size_t)g[u] * 16 + l];
        float m[8];
#pragma unroll
        for (int u = 0; u < 8; u++) m[u] = (u < rem) ? 1.f : 0.f;
#pragma unroll
        for (int j = 0; j < 8; j++) {
            float s = 0.f;
#pragma unroll
            for (int u = 0; u < 8; u++) s += m[u] * (float)v[u][j];
            a[j] += s;
        }
    }
    bf16x8 o;
#pragma unroll
    for (int j = 0; j < 8; j++) o[j] = (bf16_t)a[j];
    *((bf16x8*)(out + (size_t)seg * HDIM) + l) = o;
}

// ---------------------------------------------------------------------------
// BN finalize
// ---------------------------------------------------------------------------
__global__ void bn_finalize(const float* __restrict__ cs, const float* __restrict__ cs2,
                            const float* __restrict__ g, const float* __restrict__ b,
                            float* __restrict__ scale, float* __restrict__ shift,
                            int C, float invN) {
    int c = blockIdx.x * blockDim.x + threadIdx.x;
    if (c >= C) return;
    float m = cs[c] * invN;
    float v = cs2[c] * invN - m * m;
    float sc = g[c] * rsqrtf(v + 1e-5f);
    scale[c] = sc;
    shift[c] = b[c] - m * sc;
}

// ---------------------------------------------------------------------------
// Register-resident-weight persistent GEMM (BN stats pass only:
// flags 4|8 = column stats, no store).
// ---------------------------------------------------------------------------
template <int K, int NC>
__global__ __launch_bounds__(256, 3) void gemm_reg(
    const bf16_t* __restrict__ Ab,
    const float* __restrict__ bnScale, const float* __restrict__ bnShift,
    const bf16_t* __restrict__ Wt, const float* __restrict__ bias,
    int M,
    bf16_t* __restrict__ outB, float* __restrict__ outF,
    float* __restrict__ colsum, float* __restrict__ colsumsq,
    int bnfold, int flags) {
    constexpr int NKS = K / 32;       // k-steps
    constexpr int SLICE = NC / 4;     // cols per wave
    constexpr int NNI = SLICE / 16;   // n-frags per wave
    const int w = threadIdx.x >> 6, lane = threadIdx.x & 63;
    const int q = lane >> 4, lm = lane & 15;
    const int c0 = w * SLICE;

    bf16x8 bfr[NNI][NKS];
#pragma unroll
    for (int ni = 0; ni < NNI; ni++) {
        const bf16_t* bp = Wt + (size_t)(c0 + ni * 16 + lm) * K + q * 8;
#pragma unroll
        for (int ks = 0; ks < NKS; ks++)
            bfr[ni][ks] = *(const bf16x8*)(bp + ks * 32);
    }
    const bool doRelu = (flags & 1), doAccum = (flags & 2), doStats = (flags & 4);
    const bool doStore = !(flags & 8);
    float bv[NNI];
#pragma unroll
    for (int ni = 0; ni < NNI; ni++) bv[ni] = bias[c0 + ni * 16 + lm];
    float st1[NNI], st2[NNI];
#pragma unroll
    for (int ni = 0; ni < NNI; ni++) { st1[ni] = 0.f; st2[ni] = 0.f; }

    const int nTiles = (M + 31) >> 5;
    for (int t = blockIdx.x; t < nTiles; t += gridDim.x) {
        const int row0 = t << 5;
        bf16x8 af[2][NKS];
#pragma unroll
        for (int mi = 0; mi < 2; mi++) {
            int gr = row0 + mi * 16 + lm;
            if (gr > M - 1) gr = M - 1;
            const bf16_t* ap = Ab + (size_t)gr * K + q * 8;
#pragma unroll
            for (int ks = 0; ks < NKS; ks++)
                af[mi][ks] = *(const bf16x8*)(ap + ks * 32);
        }
        if (bnfold) {
#pragma unroll
            for (int ks = 0; ks < NKS; ks++) {
                const int kk = ks * 32 + q * 8;
                f32x4 s0 = ((const f32x4*)(bnScale + kk))[0];
                f32x4 s1v = ((const f32x4*)(bnScale + kk))[1];
                f32x4 h0 = ((const f32x4*)(bnShift + kk))[0];
                f32x4 h1 = ((const f32x4*)(bnShift + kk))[1];
                float sc8[8] = {s0[0], s0[1], s0[2], s0[3], s1v[0], s1v[1], s1v[2], s1v[3]};
                float sh8[8] = {h0[0], h0[1], h0[2], h0[3], h1[0], h1[1], h1[2], h1[3]};
#pragma unroll
                for (int mi = 0; mi < 2; mi++)
#pragma unroll
                    for (int j = 0; j < 8; j++) {
                        float f = fmaxf((float)af[mi][ks][j] * sc8[j] + sh8[j], 0.f);
                        af[mi][ks][j] = (bf16_t)f;
                    }
            }
        }
        f32x4 acc[2][NNI];
#pragma unroll
        for (int a = 0; a < 2; a++)
#pragma unroll
            for (int b = 0; b < NNI; b++) acc[a][b] = f32x4{0.f, 0.f, 0.f, 0.f};
#pragma unroll
        for (int ks = 0; ks < NKS; ks++)
#pragma unroll
            for (int ni = 0; ni < NNI; ni++) {
                acc[0][ni] = __builtin_amdgcn_mfma_f32_16x16x32_bf16(
                    af[0][ks], bfr[ni][ks], acc[0][ni], 0, 0, 0);
                acc[1][ni] = __builtin_amdgcn_mfma_f32_16x16x32_bf16(
                    af[1][ks], bfr[ni][ks], acc[1][ni], 0, 0, 0);
            }
#pragma unroll
        for (int ni = 0; ni < NNI; ni++) {
            const int col = c0 + ni * 16 + lm;
#pragma unroll
            for (int mi = 0; mi < 2; mi++) {
#pragma unroll
                for (int r = 0; r < 4; r++) {
                    const int row = row0 + mi * 16 + q * 4 + r;
                    if (row < M) {
                        float v = acc[mi][ni][r] + bv[ni];
                        if (doStats) { st1[ni] += v; st2[ni] += v * v; }
                        if (doRelu) v = fmaxf(v, 0.f);
                        if (doStore) {
                            const size_t o = (size_t)row * NC + col;
                            if (outF) {
                                outF[o] = v;
                            } else {
                                if (doAccum) v += (float)outB[o];
                                outB[o] = (bf16_t)v;
                            }
                        }
                    }
                }
            }
        }
    }
    if (doStats) {
#pragma unroll
        for (int ni = 0; ni < NNI; ni++) {
            float s1 = st1[ni], s2 = st2[ni];
            s1 += __shfl_xor(s1, 16);
            s1 += __shfl_xor(s1, 32);
            s2 += __shfl_xor(s2, 16);
            s2 += __shfl_xor(s2, 32);
            if (q == 0) {
                atomicAdd(&colsum[c0 + ni * 16 + lm], s1);
                atomicAdd(&colsumsq[c0 + ni * 16 + lm], s2);
            }
        }
    }
}

// ---------------------------------------------------------------------------
// Fused MLP: out = relu((A@W1+b1)[*bnScale+bnShift]) @ W2 + b2
// TRANSPOSED-OUTPUT variant: MFMA computed as mfma(W_frag, X_frag) so each
// thread's C-fragment holds 4 CONSECUTIVE COLUMNS at one row (A/B fragment
// layouts of 16x16x32 are structurally identical, so swapping operands
// transposes D). This packs the epilogues:
//   mid:   32x ds_write_b16  -> 8x 8B bf16x4 LDS writes
//   final: 32  scalar global -> 4x dwordx2 stores (+4 RMW loads) / dwordx4 f32
// Grid FBLK=512 (proven); LDS/barrier structure unchanged.
// flags: 1 accumulate (bf16 RMW on outB), 2 fp32 store to outF.
// ---------------------------------------------------------------------------
__global__ __launch_bounds__(256, 2) void fused_mlp(
    const bf16_t* __restrict__ Ab,
    const bf16_t* __restrict__ Wt1, const float* __restrict__ b1,
    const float* __restrict__ bnS, const float* __restrict__ bnH,
    const bf16_t* __restrict__ Wt2, const float* __restrict__ b2,
    int M,
    bf16_t* __restrict__ outB, float* __restrict__ outF,
    int bnfold, int flags) {
    __shared__ char hs[2][32 * 512];  // 2 x (32 rows x 256 bf16)
    const int w = threadIdx.x >> 6, lane = threadIdx.x & 63;
    const int q = lane >> 4, lm = lane & 15;
    const int c0h = w * 64;   // wave's H2-column slice
    const int c0o = w * 32;   // wave's out-column slice

    // resident W1 slice: 4 n-frags x 4 k-steps = 64 VGPRs
    bf16x8 bfr1[4][4];
#pragma unroll
    for (int ni = 0; ni < 4; ni++) {
        const bf16_t* bp = Wt1 + (size_t)(c0h + ni * 16 + lm) * 128 + q * 8;
#pragma unroll
        for (int ks = 0; ks < 4; ks++) bfr1[ni][ks] = *(const bf16x8*)(bp + ks * 32);
    }
    // resident W2 slice: 2 n-frags x 8 k-steps = 64 VGPRs
    bf16x8 bfr2[2][8];
#pragma unroll
    for (int ni = 0; ni < 2; ni++) {
        const bf16_t* bp = Wt2 + (size_t)(c0o + ni * 16 + lm) * 256 + q * 8;
#pragma unroll
        for (int ks = 0; ks < 8; ks++) bfr2[ni][ks] = *(const bf16x8*)(bp + ks * 32);
    }
    // per-thread bias/BN vectors over 4 consecutive columns (q*4 base)
    f32x4 bv1[4], bsc[4], bsh[4];
#pragma unroll
    for (int ni = 0; ni < 4; ni++) {
        const int c = c0h + ni * 16 + q * 4;
        bv1[ni] = *(const f32x4*)(b1 + c);
        if (bnfold) {
            bsc[ni] = *(const f32x4*)(bnS + c);
            bsh[ni] = *(const f32x4*)(bnH + c);
        } else {
            bsc[ni] = f32x4{1.f, 1.f, 1.f, 1.f};
            bsh[ni] = f32x4{0.f, 0.f, 0.f, 0.f};
        }
    }
    f32x4 bv2[2];
#pragma unroll
    for (int ni = 0; ni < 2; ni++) bv2[ni] = *(const f32x4*)(b2 + c0o + ni * 16 + q * 4);

    const bool doAccum = (flags & 1), f32out = (flags & 2);
    const int nTiles = (M + 31) >> 5;
    int buf = 0;
    for (int t = blockIdx.x; t < nTiles; t += gridDim.x, buf ^= 1) {
        const int row0 = t << 5;
        char* hb = hs[buf];
        // ---- GEMM1: h^T frags = mfma(W1_frag, X_frag) ----
        bf16x8 af[2][4];
#pragma unroll
        for (int mi = 0; mi < 2; mi++) {
            int gr = row0 + mi * 16 + lm;
            if (gr > M - 1) gr = M - 1;  // clamp; stores guarded below
            const bf16_t* ap = Ab + (size_t)gr * 128 + q * 8;
#pragma unroll
            for (int ks = 0; ks < 4; ks++) af[mi][ks] = *(const bf16x8*)(ap + ks * 32);
        }
        f32x4 acc1[2][4];
#pragma unroll
        for (int a = 0; a < 2; a++)
#pragma unroll
            for (int b = 0; b < 4; b++) acc1[a][b] = f32x4{0.f, 0.f, 0.f, 0.f};
#pragma unroll
        for (int ks = 0; ks < 4; ks++)
#pragma unroll
            for (int ni = 0; ni < 4; ni++) {
                acc1[0][ni] = __builtin_amdgcn_mfma_f32_16x16x32_bf16(
                    bfr1[ni][ks], af[0][ks], acc1[0][ni], 0, 0, 0);
                acc1[1][ni] = __builtin_amdgcn_mfma_f32_16x16x32_bf16(
                    bfr1[ni][ks], af[1][ks], acc1[1][ni], 0, 0, 0);
            }
        // ---- mid epilogue: acc1[mi][ni][r] = h[row=mi*16+lm][c0h+ni*16+q*4+r]
        //      bias+BN+relu, pack 4 cols -> one 8B swizzled LDS write ----
#pragma unroll
        for (int mi = 0; mi < 2; mi++) {
            const int row = mi * 16 + lm;
            const int swz = ((row & 7) << 4) ^ ((row & 8) << 2);
            char* rowp = hb + (row << 9);
#pragma unroll
            for (int ni = 0; ni < 4; ni++) {
                const int cb = (c0h + ni * 16 + q * 4) * 2;
                bf16x4 pk;
#pragma unroll
                for (int r = 0; r < 4; r++) {
                    float v = (acc1[mi][ni][r] + bv1[ni][r]) * bsc[ni][r] + bsh[ni][r];
                    pk[r] = (bf16_t)fmaxf(v, 0.f);
                }
                *(bf16x4*)(rowp + (cb ^ swz)) = pk;
            }
        }
        __syncthreads();
        // ---- GEMM2: out^T frags = mfma(W2_frag, h_frag) ----
        f32x4 acc2[2][2];
#pragma unroll
        for (int a = 0; a < 2; a++)
#pragma unroll
            for (int b = 0; b < 2; b++) acc2[a][b] = f32x4{0.f, 0.f, 0.f, 0.f};
#pragma unroll
        for (int ks = 0; ks < 8; ks++) {
            const int ko = ks * 64 + q * 16;
            const int r0 = lm, r1 = lm + 16;
            const int s0 = ((r0 & 7) << 4) ^ ((r0 & 8) << 2);
            const int s1 = ((r1 & 7) << 4) ^ ((r1 & 8) << 2);
            bf16x8 a0 = *(const bf16x8*)(hb + (r0 << 9) + (ko ^ s0));
            bf16x8 a1 = *(const bf16x8*)(hb + (r1 << 9) + (ko ^ s1));
#pragma unroll
            for (int ni = 0; ni < 2; ni++) {
                acc2[0][ni] = __builtin_amdgcn_mfma_f32_16x16x32_bf16(
                    bfr2[ni][ks], a0, acc2[0][ni], 0, 0, 0);
                acc2[1][ni] = __builtin_amdgcn_mfma_f32_16x16x32_bf16(
                    bfr2[ni][ks], a1, acc2[1][ni], 0, 0, 0);
            }
        }
        // ---- final epilogue: acc2[mi][ni][r] = out[row0+mi*16+lm][c0o+ni*16+q*4+r]
        //      4 consecutive cols -> vectorized global store ----
#pragma unroll
        for (int mi = 0; mi < 2; mi++) {
            const int row = row0 + mi * 16 + lm;
            if (row < M) {
#pragma unroll
                for (int ni = 0; ni < 2; ni++) {
                    const int col = c0o + ni * 16 + q * 4;
                    const size_t o = (size_t)row * 128 + col;
                    if (f32out) {
                        f32x4 v;
#pragma unroll
                        for (int r = 0; r < 4; r++) v[r] = acc2[mi][ni][r] + bv2[ni][r];
                        *(f32x4*)(outF + o) = v;
                    } else {
                        bf16x4 pk;
                        if (doAccum) {
                            bf16x4 old = *(const bf16x4*)(outB + o);
#pragma unroll
                            for (int r = 0; r < 4; r++)
                                pk[r] = (bf16_t)(acc2[mi][ni][r] + bv2[ni][r] + (float)old[r]);
                        } else {
#pragma unroll
                            for (int r = 0; r < 4; r++)
                                pk[r] = (bf16_t)(acc2[mi][ni][r] + bv2[ni][r]);
                        }
                        *(bf16x4*)(outB + o) = pk;
                    }
                }
            }
        }
        // no trailing barrier: next tile writes the other LDS buffer; the
        // barrier inside iteration t+1 orders read(t) before write(t+2).
    }
}

// ---------------------------------------------------------------------------
extern "C" void kernel_launch(void* const* d_in, const int* in_sizes, int n_in,
                              void* d_out, int out_size, void* d_ws, size_t ws_size,
                              hipStream_t stream) {
    const float* x_in   = (const float*)d_in[0];
    const int*   ei     = (const int*)d_in[1];
    const int*   se0    = (const int*)d_in[2];
    const int*   se1    = (const int*)d_in[3];
    const float* msg_w1 = (const float*)d_in[4];
    const float* msg_b1 = (const float*)d_in[5];
    const float* bn_g   = (const float*)d_in[6];
    const float* bn_b   = (const float*)d_in[7];
    const float* msg_w2 = (const float*)d_in[8];
    const float* msg_b2 = (const float*)d_in[9];
    const float* eps_g  = (const float*)d_in[10];
    const float* n2s_w1 = (const float*)d_in[11];
    const float* n2s_b1 = (const float*)d_in[12];
    const float* n2s_w2 = (const float*)d_in[13];
    const float* n2s_b2 = (const float*)d_in[14];
    const float* s2n_w1 = (const float*)d_in[15];
    const float* s2n_b1 = (const float*)d_in[16];
    const float* s2n_w2 = (const float*)d_in[17];
    const float* s2n_b2 = (const float*)d_in[18];
    const float* out_w1 = (const float*)d_in[19];
    const float* out_b1 = (const float*)d_in[20];
    const float* out_w2 = (const float*)d_in[21];
    const float* out_b2 = (const float*)d_in[22];
    float* out = (float*)d_out;

    char* ws = (char*)d_ws;
    size_t off = 0;
    auto alloc = [&](size_t bytes) -> char* {
        char* p = ws + off;
        off += (bytes + 255) & ~(size_t)255;
        return p;
    };
    bf16_t* xbf   = (bf16_t*)alloc((size_t)N_NODES * HDIM * 2);   // residual x (bf16)
    bf16_t* xcomb = (bf16_t*)alloc((size_t)N_NODES * HDIM * 2);   // gin-comb / s2n msg
    bf16_t* sxsum = (bf16_t*)alloc((size_t)NSUB_G * HDIM * 2);
    bf16_t* sxout = (bf16_t*)alloc((size_t)NSUB_G * HDIM * 2);
    const size_t WSZ = (size_t)HDIM * H2DIM;
    bf16_t* wt_msg1 = (bf16_t*)alloc(NLAYER * WSZ * 2);
    bf16_t* wt_msg2 = (bf16_t*)alloc(NLAYER * WSZ * 2);
    bf16_t* wt_n2s1 = (bf16_t*)alloc(NLAYER * NSUBT * WSZ * 2);
    bf16_t* wt_n2s2 = (bf16_t*)alloc(NLAYER * NSUBT * WSZ * 2);
    bf16_t* wt_s2n1 = (bf16_t*)alloc(NLAYER * NSUBT * WSZ * 2);
    bf16_t* wt_s2n2 = (bf16_t*)alloc(NLAYER * NSUBT * WSZ * 2);
    bf16_t* wt_out1 = (bf16_t*)alloc(WSZ * 2);
    bf16_t* wt_out2 = (bf16_t*)alloc(WSZ * 2);
    float* colsum   = (float*)alloc(H2DIM * 4);
    float* colsumsq = (float*)alloc(H2DIM * 4);
    float* bnscale  = (float*)alloc(H2DIM * 4);
    float* bnshift  = (float*)alloc(H2DIM * 4);
    int* rp_gin   = (int*)alloc((N_NODES + 1) * 4);
    int* gat_gin  = (int*)alloc((size_t)E_EDGES * 4);
    int* rp_n2s0  = (int*)alloc((NSUB_G + 1) * 4);
    int* gat_n2s0 = (int*)alloc((size_t)ESUB_E * 4);
    int* rp_n2s1  = (int*)alloc((NSUB_G + 1) * 4);
    int* gat_n2s1 = (int*)alloc((size_t)ESUB_E * 4);
    int* rp_s2n0  = (int*)alloc((N_NODES + 1) * 4);
    int* gat_s2n0 = (int*)alloc((size_t)ESUB_E * 4);
    int* rp_s2n1  = (int*)alloc((N_NODES + 1) * 4);
    int* gat_s2n1 = (int*)alloc((size_t)ESUB_E * 4);
    int* counts  = (int*)alloc((N_NODES + 1) * 4);
    int* partial = (int*)alloc((size_t)N_NODES * 4);
    int* bsum    = (int*)alloc(512 * 4);
    (void)ws_size; (void)in_sizes; (void)n_in; (void)out_size;

    auto tr = [&](const float* W, bf16_t* Wt, int K, int Nc, int batch) {
        long total = (long)batch * K * Nc;
        int blocks = (int)((total + 255) / 256);
        transpose_w<<<blocks, 256, 0, stream>>>(W, Wt, K, Nc, total);
    };
    tr(msg_w1, wt_msg1, HDIM, H2DIM, NLAYER);
    tr(msg_w2, wt_msg2, H2DIM, HDIM, NLAYER);
    tr(n2s_w1, wt_n2s1, HDIM, H2DIM, NLAYER * NSUBT);
    tr(n2s_w2, wt_n2s2, H2DIM, HDIM, NLAYER * NSUBT);
    tr(s2n_w1, wt_s2n1, HDIM, H2DIM, NLAYER * NSUBT);
    tr(s2n_w2, wt_s2n2, H2DIM, HDIM, NLAYER * NSUBT);
    tr(out_w1, wt_out1, HDIM, H2DIM, 1);
    tr(out_w2, wt_out2, H2DIM, OUTD, 1);

    auto build_csr = [&](const int* idx, const int* gsrc, int nE, int nseg,
                         int* rowptr, int* gat) {
        hipMemsetAsync(counts, 0, (size_t)nseg * 4, stream);
        hist_k<<<(nE + 255) / 256, 256, 0, stream>>>(idx, counts, nE);
        int nb = (nseg + 1023) / 1024;
        scan1_k<<<nb, 256, 0, stream>>>(counts, partial, bsum, nseg);
        scan2_k<<<1, 256, 0, stream>>>(bsum, nb);
        scan3_k<<<(nseg + 255) / 256, 256, 0, stream>>>(partial, bsum, rowptr,
                                                        counts, nseg, nE);
        csr_place<<<(nE + 255) / 256, 256, 0, stream>>>(idx, gsrc, counts, gat, nE);
    };
    const int* src = ei;
    const int* dst = ei + E_EDGES;
    build_csr(dst, src, E_EDGES, N_NODES, rp_gin, gat_gin);
    build_csr(se0 + ESUB_E, se0, ESUB_E, NSUB_G, rp_n2s0, gat_n2s0);
    build_csr(se1 + ESUB_E, se1, ESUB_E, NSUB_G, rp_n2s1, gat_n2s1);
    build_csr(se0, se0 + ESUB_E, ESUB_E, N_NODES, rp_s2n0, gat_s2n0);
    build_csr(se1, se1 + ESUB_E, ESUB_E, N_NODES, rp_s2n1, gat_s2n1);

    {
        long n = (long)N_NODES * HDIM;
        cast_f2b<<<(int)((n / 4 + 255) / 256), 256, 0, stream>>>(x_in, xbf, n);
    }

    // stats-only gemm (K=128, NC=256)
    auto gemmStats = [&](const bf16_t* Ab, const bf16_t* Wt, const float* bias,
                         int M, float* cs, float* cs2) {
        int nt = (M + 31) / 32;
        int g = nt < NBLK ? nt : NBLK;
        gemm_reg<128, 256><<<g, 256, 0, stream>>>(
            Ab, nullptr, nullptr, Wt, bias, M, nullptr, nullptr, cs, cs2, 0, 4 | 8);
    };
    // fused MLP
    auto fmlp = [&](const bf16_t* Ab, const bf16_t* W1t, const float* b1p,
                    const float* bnS, const float* bnH,
                    const bf16_t* W2t, const float* b2p, int M,
                    bf16_t* oB, float* oF, int bnfold, int flags) {
        int nt = (M + 31) / 32;
        int g = nt < FBLK ? nt : FBLK;
        fused_mlp<<<g, 256, 0, stream>>>(Ab, W1t, b1p, bnS, bnH, W2t, b2p, M,
                                         oB, oF, bnfold, flags);
    };

    for (int i = 0; i < NLAYER; i++) {
        // GIN aggregation fused with (1+eps)x combine -> bf16
        segsum_ginb<<<(N_NODES + 15) / 16, 256, 0, stream>>>(
            xbf, eps_g + i, rp_gin, gat_gin, xcomb, N_NODES);
        // pass 1: column stats of h = xcomb@W1+b1 (no h write)
        hipMemsetAsync(colsum, 0, H2DIM * 4, stream);
        hipMemsetAsync(colsumsq, 0, H2DIM * 4, stream);
        gemmStats(xcomb, wt_msg1 + (size_t)i * WSZ, msg_b1 + (size_t)i * H2DIM,
                  N_NODES, colsum, colsumsq);
        bn_finalize<<<1, 256, 0, stream>>>(colsum, colsumsq, bn_g + (size_t)i * H2DIM,
                                           bn_b + (size_t)i * H2DIM, bnscale, bnshift,
                                           H2DIM, 1.0f / N_NODES);
        // pass 2: x = relu(BN(xcomb@W1+b1)) @ W2 + b2 fused
        fmlp(xcomb, wt_msg1 + (size_t)i * WSZ, msg_b1 + (size_t)i * H2DIM,
             bnscale, bnshift,
             wt_msg2 + (size_t)i * WSZ, msg_b2 + (size_t)i * HDIM,
             N_NODES, xbf, nullptr, 1, 0);

        for (int s = 0; s < NSUBT; s++) {
            const int* rp_n2s = (s == 0 ? rp_n2s0 : rp_n2s1);
            const int* gt_n2s = (s == 0 ? gat_n2s0 : gat_n2s1);
            const int* rp_s2n = (s == 0 ? rp_s2n0 : rp_s2n1);
            const int* gt_s2n = (s == 0 ? gat_s2n0 : gat_s2n1);
            const size_t widx = ((size_t)i * NSUBT + s) * WSZ;
            const size_t b1o = ((size_t)i * NSUBT + s) * H2DIM;
            const size_t b2o = ((size_t)i * NSUBT + s) * HDIM;
            // sx = segment_sum(x[row], col)
            segsum_b16<<<(NSUB_G + 15) / 16, 256, 0, stream>>>(
                xbf, rp_n2s, gt_n2s, sxsum, NSUB_G);
            // sx = relu(sx@w1+b1)@w2+b2  (fused)
            fmlp(sxsum, wt_n2s1 + widx, n2s_b1 + b1o, nullptr, nullptr,
                 wt_n2s2 + widx, n2s_b2 + b2o, NSUB_G, sxout, nullptr, 0, 0);
            // msg = segment_sum(sx[col], row)
            segsum_b16<<<(N_NODES + 15) / 16, 256, 0, stream>>>(
                sxout, rp_s2n, gt_s2n, xcomb, N_NODES);
            // x += relu(msg@w1+b1)@w2+b2  (fused, accumulate)
            fmlp(xcomb, wt_s2n1 + widx, s2n_b1 + b1o, nullptr, nullptr,
                 wt_s2n2 + widx, s2n_b2 + b2o, N_NODES, xbf, nullptr, 0, 1);
        }
    }
    // output head (fused, fp32 out)
    fmlp(xbf, wt_out1, out_b1, nullptr, nullptr, wt_out2, out_b2,
         N_NODES, nullptr, out, 0, 2);
}